// Round 1
// baseline (2212.497 us; speedup 1.0000x reference)
//
#include <hip/hip_runtime.h>

#define Bb    128
#define Nn    512
#define Fdim  8
#define Hh    128
#define ITERS 3
#define ROWS  (Bb*Nn)

// ---------------------------------------------------------------- embed L1
// out[row][c] = relu(sum_f jets[row][f]*W0[f][c] + b0[c])
__global__ __launch_bounds__(256) void embed1_kernel(
    const float* __restrict__ jets, const float* __restrict__ W0,
    const float* __restrict__ b0, float* __restrict__ out) {
  __shared__ float sW0[Fdim*Hh];
  __shared__ float sb0[Hh];
  int t = threadIdx.x;
  for (int i = t; i < Fdim*Hh; i += 256) sW0[i] = W0[i];
  if (t < Hh) sb0[t] = b0[t];
  __syncthreads();
  int g = t >> 7, c = t & 127;
  int base = blockIdx.x * 8;
  for (int rr = 0; rr < 8; rr += 2) {
    int row = base + rr + g;
    const float* x = jets + row*Fdim;
    float acc = sb0[c];
#pragma unroll
    for (int f = 0; f < Fdim; ++f) acc = fmaf(x[f], sW0[f*Hh + c], acc);
    out[row*Hh + c] = fmaxf(acc, 0.f);
  }
}

// ---------------------------------------------------------------- dense
// C[row][c] = relu( sum_j A[row][j] * W[j][c] + bias[c] )  (* mask[row] opt)
// A = A0 (first 128 cols) [+ A1 (next 128 cols) when K==256]
// W (K x 128) kept in LDS. 128 rows per block, 4-row chunks,
// each thread owns 2 cols (c, c+64) of 1 row-slot g = tid>>6.
template<int K, bool MASKMUL>
__global__ __launch_bounds__(256) void dense_kernel(
    const float* __restrict__ A0, const float* __restrict__ A1,
    const float* __restrict__ W, const float* __restrict__ bias,
    const float* __restrict__ mask, float* __restrict__ C) {
  __shared__ float sW[K*128];
  __shared__ float sb[128];
  __shared__ float sa[4][K];
  int t = threadIdx.x;
  for (int i = t; i < K*128; i += 256) sW[i] = W[i];
  if (t < 128) sb[t] = bias[t];
  __syncthreads();
  const int row0 = blockIdx.x * 128;
  const int g = t >> 6;
  const int c = t & 63;
  for (int rr = 0; rr < 128; rr += 4) {
    // stage 4 input rows
#pragma unroll
    for (int q = 0; q < (4*K)/256; ++q) {
      int e = t + q*256;
      int r = e / K, j = e % K;
      float v;
      if (j < 128) v = A0[(row0+rr+r)*128 + j];
      else         v = A1[(row0+rr+r)*128 + (j-128)];
      sa[r][j] = v;
    }
    __syncthreads();
    int row = row0 + rr + g;
    float acc0 = sb[c], acc1 = sb[c+64];
#pragma unroll 4
    for (int j = 0; j < K; ++j) {
      float av = sa[g][j];
      acc0 = fmaf(av, sW[j*128 + c],      acc0);
      acc1 = fmaf(av, sW[j*128 + c + 64], acc1);
    }
    acc0 = fmaxf(acc0, 0.f); acc1 = fmaxf(acc1, 0.f);
    if (MASKMUL) { float mv = mask[row]; acc0 *= mv; acc1 *= mv; }
    C[row*128 + c]      = acc0;
    C[row*128 + c + 64] = acc1;
    __syncthreads();
  }
}

// ---------------------------------------------------------------- adjacency stats
// S'_ij = 2*dot(x_i,x_j) - (|x_j|^2 + maskpen_j);  m_i = max_j S', l_i = sum exp(S'-m)
__global__ __launch_bounds__(256) void adjstats_kernel(
    const float* __restrict__ jets, const float* __restrict__ mask,
    float* __restrict__ marr, float* __restrict__ larr) {
  __shared__ float Xs[Nn*9];
  __shared__ float cb[Nn];
  int t = threadIdx.x;
  int b = blockIdx.x >> 7;        // 128 itiles per batch
  int itile = blockIdx.x & 127;
  const float* jb = jets + b*Nn*Fdim;
  for (int j = t; j < Nn; j += 256) {
    float s2 = 0.f;
#pragma unroll
    for (int f = 0; f < Fdim; ++f) { float v = jb[j*Fdim+f]; Xs[j*9+f] = v; s2 = fmaf(v,v,s2); }
    cb[j] = s2 + (mask[b*Nn+j] > 0.f ? 0.f : 1e9f);
  }
  __syncthreads();
  int w = t >> 6, lane = t & 63;
  int i = itile*4 + w;
  float xi[Fdim];
#pragma unroll
  for (int f = 0; f < Fdim; ++f) xi[f] = Xs[i*9+f];
  float s[8];
#pragma unroll
  for (int it = 0; it < 8; ++it) {
    int j = lane + it*64;
    float d = 0.f;
#pragma unroll
    for (int f = 0; f < Fdim; ++f) d = fmaf(xi[f], Xs[j*9+f], d);
    s[it] = 2.f*d - cb[j];
  }
  float mx = s[0];
#pragma unroll
  for (int it = 1; it < 8; ++it) mx = fmaxf(mx, s[it]);
  for (int o = 32; o; o >>= 1) mx = fmaxf(mx, __shfl_xor(mx, o, 64));
  float sum = 0.f;
#pragma unroll
  for (int it = 0; it < 8; ++it) sum += __expf(s[it]-mx);
  for (int o = 32; o; o >>= 1) sum += __shfl_xor(sum, o, 64);
  if (lane == 0) { marr[b*Nn+i] = mx; larr[b*Nn+i] = sum; }
}

// ---------------------------------------------------------------- agg = P @ msg
// block: (batch b, 32-row i-chunk). j streamed in 32-tiles.
__global__ __launch_bounds__(256) void agg_kernel(
    const float* __restrict__ jets, const float* __restrict__ mask,
    const float* __restrict__ marr, const float* __restrict__ larr,
    const float* __restrict__ msg, float* __restrict__ agg) {
  __shared__ float Xs[Nn*9];
  __shared__ float cb[Nn];
  __shared__ float P[32*32];
  __shared__ float Mt[32*128];
  __shared__ float mi[32], ri[32];
  int t = threadIdx.x;
  int b  = blockIdx.x >> 4;       // 16 ichunks per batch
  int ic = blockIdx.x & 15;
  int i0 = ic * 32;
  const float* jb = jets + b*Nn*Fdim;
  for (int j = t; j < Nn; j += 256) {
    float s2 = 0.f;
#pragma unroll
    for (int f = 0; f < Fdim; ++f) { float v = jb[j*Fdim+f]; Xs[j*9+f] = v; s2 = fmaf(v,v,s2); }
    cb[j] = s2 + (mask[b*Nn+j] > 0.f ? 0.f : 1e9f);
  }
  if (t < 32) { mi[t] = marr[b*Nn+i0+t]; ri[t] = 1.f/larr[b*Nn+i0+t]; }
  __syncthreads();
  const int g = t >> 6;           // row group 0..3 (8 rows each)
  const int c = t & 63;           // cols c, c+64
  float acc0[8], acc1[8];
#pragma unroll
  for (int r = 0; r < 8; ++r) { acc0[r]=0.f; acc1[r]=0.f; }
  for (int jt = 0; jt < Nn/32; ++jt) {
    // stage 32x128 msg tile
#pragma unroll
    for (int q = 0; q < 16; ++q) {
      int e = t + q*256;
      Mt[e] = msg[(b*Nn + jt*32 + (e>>7))*128 + (e&127)];
    }
    // compute 32x32 P tile
#pragma unroll
    for (int q = 0; q < 4; ++q) {
      int e = t + q*256;
      int ii = e >> 5, jj = e & 31;
      int i = i0 + ii, j = jt*32 + jj;
      float d = 0.f;
#pragma unroll
      for (int f = 0; f < Fdim; ++f) d = fmaf(Xs[i*9+f], Xs[j*9+f], d);
      P[e] = __expf(2.f*d - cb[j] - mi[ii]) * ri[ii];
    }
    __syncthreads();
#pragma unroll 2
    for (int jj = 0; jj < 32; ++jj) {
      float m0 = Mt[jj*128 + c];
      float m1 = Mt[jj*128 + c + 64];
#pragma unroll
      for (int r = 0; r < 8; ++r) {
        float p = P[(g*8+r)*32 + jj];
        acc0[r] = fmaf(p, m0, acc0[r]);
        acc1[r] = fmaf(p, m1, acc1[r]);
      }
    }
    __syncthreads();
  }
#pragma unroll
  for (int r = 0; r < 8; ++r) {
    int row = b*Nn + i0 + g*8 + r;
    agg[row*128 + c]      = acc0[r];
    agg[row*128 + c + 64] = acc1[r];
  }
}

// ---------------------------------------------------------------- pool
__global__ __launch_bounds__(256) void pool_kernel(
    const float* __restrict__ h, const float* __restrict__ mask,
    float* __restrict__ pooled) {
  __shared__ float part[128];
  int b = blockIdx.x;
  int t = threadIdx.x, g = t>>7, c = t&127;
  float acc = 0.f;
  for (int n = g*256; n < g*256+256; ++n)
    acc = fmaf(h[(b*Nn+n)*128 + c], mask[b*Nn+n], acc);
  if (g == 1) part[c] = acc;
  __syncthreads();
  if (g == 0) pooled[b*128 + c] = acc + part[c];
}

// ---------------------------------------------------------------- readout
__global__ __launch_bounds__(256) void readout_kernel(
    const float* __restrict__ pooled, const float* __restrict__ W1,
    const float* __restrict__ b1, const float* __restrict__ W2,
    const float* __restrict__ b2, float* __restrict__ out) {
  __shared__ float pl[128], hid[128];
  int b = blockIdx.x, t = threadIdx.x;   // 128 threads
  pl[t] = pooled[b*128 + t];
  __syncthreads();
  float acc = b1[t];
#pragma unroll 4
  for (int j = 0; j < 128; ++j) acc = fmaf(pl[j], W1[j*128 + t], acc);
  hid[t] = fmaxf(acc, 0.f);
  __syncthreads();
  float acc2 = b2[t];
#pragma unroll 4
  for (int j = 0; j < 128; ++j) acc2 = fmaf(hid[j], W2[j*128 + t], acc2);
  out[b*128 + t] = acc2;
}

// ---------------------------------------------------------------- launch
extern "C" void kernel_launch(void* const* d_in, const int* in_sizes, int n_in,
                              void* d_out, int out_size, void* d_ws, size_t ws_size,
                              hipStream_t stream) {
  const float* jets = (const float*)d_in[0];
  const float* mask = (const float*)d_in[1];
  const float* eW0  = (const float*)d_in[2];
  const float* eb0  = (const float*)d_in[3];
  const float* eW1  = (const float*)d_in[4];
  const float* eb1  = (const float*)d_in[5];
  const float* Wm   = (const float*)d_in[6];
  const float* bm   = (const float*)d_in[7];
  const float* Wu   = (const float*)d_in[8];
  const float* bu   = (const float*)d_in[9];
  const float* rW1  = (const float*)d_in[10];
  const float* rb1  = (const float*)d_in[11];
  const float* rW2  = (const float*)d_in[12];
  const float* rb2  = (const float*)d_in[13];
  float* out = (float*)d_out;

  float* ws     = (float*)d_ws;
  float* h      = ws;                      // ROWS*128
  float* msg    = h    + (size_t)ROWS*128;
  float* agg    = msg  + (size_t)ROWS*128;
  float* marr   = agg  + (size_t)ROWS*128; // ROWS
  float* larr   = marr + ROWS;
  float* pooled = larr + ROWS;             // B*128

  // embedding: L1 into msg (temp), L2 into h
  embed1_kernel<<<ROWS/8, 256, 0, stream>>>(jets, eW0, eb0, msg);
  dense_kernel<128,false><<<ROWS/128, 256, 0, stream>>>(msg, nullptr, eW1, eb1, nullptr, h);
  // adjacency softmax stats (iteration-invariant)
  adjstats_kernel<<<Bb*(Nn/4), 256, 0, stream>>>(jets, mask, marr, larr);

  for (int it = 0; it < ITERS; ++it) {
    dense_kernel<128,false><<<ROWS/128, 256, 0, stream>>>(h, nullptr, Wm + it*Hh*Hh, bm + it*Hh, nullptr, msg);
    agg_kernel<<<Bb*(Nn/32), 256, 0, stream>>>(jets, mask, marr, larr, msg, agg);
    dense_kernel<256,true><<<ROWS/128, 256, 0, stream>>>(h, agg, Wu + it*2*Hh*Hh, bu + it*Hh, mask, h);
  }

  pool_kernel<<<Bb, 256, 0, stream>>>(h, mask, pooled);
  readout_kernel<<<Bb, 128, 0, stream>>>(pooled, rW1, rb1, rW2, rb2, out);
}

// Round 2
// 372.447 us; speedup vs baseline: 5.9404x; 5.9404x over previous
//
#include <hip/hip_runtime.h>
#include <stdint.h>
#include <stddef.h>

#define Bb 128
#define Nn 512
#define Hh 128
#define ROWS (Bb*Nn)

typedef __bf16 bf16;
typedef __bf16 bf16x2 __attribute__((ext_vector_type(2)));
typedef __bf16 bf16x4 __attribute__((ext_vector_type(4)));
typedef __bf16 bf16x8 __attribute__((ext_vector_type(8)));
typedef float  f32x4  __attribute__((ext_vector_type(4)));

__device__ __forceinline__ void glds16(const void* g, void* l) {
  __builtin_amdgcn_global_load_lds(
      (const __attribute__((address_space(1))) void*)g,
      (__attribute__((address_space(3))) void*)l, 16, 0, 0);
}

// -------------------------------------------------- weight prep: fp32 W[k][c]
// -> bf16 W^T[c][k] with XOR swizzle (k ^ ((c&7)<<3)) pre-applied so the dense
// kernel can stage linearly via global_load_lds and ds_read_b128 conflict-free.
__global__ __launch_bounds__(256) void prep_wt(const float* __restrict__ src,
                                               bf16* __restrict__ dst,
                                               int K, int total) {
  int idx = blockIdx.x*256 + threadIdx.x;
  if (idx >= total) return;
  int mk = K*128;
  int m = idx / mk, rem = idx - m*mk;
  int k = rem >> 7, c = rem & 127;
  dst[m*mk + c*K + (k ^ ((c & 7) << 3))] = (bf16)src[idx];
}

// -------------------------------------------------- embed layer 1 (K=8, VALU)
__global__ __launch_bounds__(256) void embed1_kernel(
    const float* __restrict__ jets, const float* __restrict__ W0,
    const float* __restrict__ b0, bf16* __restrict__ out) {
  __shared__ float sW[8*128];
  __shared__ float sb[128];
  int t = threadIdx.x;
  for (int i = t; i < 8*128; i += 256) sW[i] = W0[i];
  if (t < 128) sb[t] = b0[t];
  __syncthreads();
  int row = blockIdx.x*4 + (t >> 6);
  int cp  = (t & 63)*2;
  const float* x = jets + (size_t)row*8;
  float a0 = sb[cp], a1 = sb[cp+1];
#pragma unroll
  for (int f = 0; f < 8; ++f) {
    float xv = x[f];
    a0 = fmaf(xv, sW[f*128+cp],   a0);
    a1 = fmaf(xv, sW[f*128+cp+1], a1);
  }
  bf16x2 o; o[0] = (bf16)fmaxf(a0,0.f); o[1] = (bf16)fmaxf(a1,0.f);
  *(bf16x2*)(out + (size_t)row*128 + cp) = o;
}

// -------------------------------------------------- MFMA dense
// out = relu(A @ W + b) [*mask].  A = A0 (k<128) / A1 (k>=128), bf16 row-major.
// W^T bf16 swizzled resident in LDS. Block: 128 rows x 128 cols, 4 waves 2x2.
// TRANSOUT=0: mfma(Wfrag, Afrag) -> lane holds 4 consecutive cols -> row-major out.
// TRANSOUT=1: mfma(Afrag, Wfrag) -> lane holds 4 consecutive rows -> writes msgT[c][r].
template<int K, bool MASKMUL, bool TRANSOUT>
__global__ __launch_bounds__(256) void mfma_dense(
    const bf16* __restrict__ A0, const bf16* __restrict__ A1,
    const bf16* __restrict__ WT, const float* __restrict__ bias,
    const float* __restrict__ mask, bf16* __restrict__ out) {
  __shared__ bf16 sWT[128*K];
  const int t = threadIdx.x;
  const int w = t >> 6, lane = t & 63;
  const int l15 = lane & 15, g = lane >> 4;
  const int CH = (128*K*2)/1024;          // 1 KB per wave-instr
  for (int q = w; q < CH; q += 4)
    glds16((const char*)WT + q*1024 + lane*16, (char*)(void*)sWT + q*1024);

  const int row_blk = blockIdx.x*128;
  const int wr = (w & 1)*64, wc = (w >> 1)*64;
  int rowg[4];
#pragma unroll
  for (int n = 0; n < 4; ++n) rowg[n] = row_blk + wr + n*16 + l15;
  f32x4 acc[4][4];
#pragma unroll
  for (int m = 0; m < 4; ++m)
#pragma unroll
    for (int n = 0; n < 4; ++n) acc[m][n] = (f32x4){0.f,0.f,0.f,0.f};
  __syncthreads();

#pragma unroll
  for (int kk = 0; kk < K; kk += 32) {
    const bf16* base; int kl;
    if (K == 128) { base = A0; kl = kk; }
    else          { base = (kk < 128) ? A0 : A1; kl = kk & 127; }
    bf16x8 bfr[4];
#pragma unroll
    for (int n = 0; n < 4; ++n)
      bfr[n] = *(const bf16x8*)(base + (size_t)rowg[n]*128 + kl + 8*g);
    bf16x8 wfr[4];
#pragma unroll
    for (int m = 0; m < 4; ++m) {
      int c = wc + m*16 + l15;
      int kidx = (kk + 8*g) ^ ((c & 7) << 3);
      wfr[m] = *(const bf16x8*)(sWT + c*K + kidx);
    }
#pragma unroll
    for (int m = 0; m < 4; ++m)
#pragma unroll
      for (int n = 0; n < 4; ++n) {
        if (TRANSOUT)
          acc[m][n] = __builtin_amdgcn_mfma_f32_16x16x32_bf16(bfr[n], wfr[m], acc[m][n], 0,0,0);
        else
          acc[m][n] = __builtin_amdgcn_mfma_f32_16x16x32_bf16(wfr[m], bfr[n], acc[m][n], 0,0,0);
      }
  }

  if (!TRANSOUT) {
#pragma unroll
    for (int m = 0; m < 4; ++m) {
      f32x4 bs = *(const f32x4*)(bias + wc + m*16 + g*4);
#pragma unroll
      for (int n = 0; n < 4; ++n) {
        int r = rowg[n];
        float mv = MASKMUL ? mask[r] : 1.f;
        f32x4 v = acc[m][n];
        bf16x4 o;
#pragma unroll
        for (int j = 0; j < 4; ++j) {
          float x = fmaxf(v[j] + bs[j], 0.f);
          if (MASKMUL) x *= mv;
          o[j] = (bf16)x;
        }
        *(bf16x4*)(out + (size_t)r*128 + wc + m*16 + g*4) = o;
      }
    }
  } else {
    const int b = row_blk >> 9;
    const int rbase = (row_blk & 511) + wr;
#pragma unroll
    for (int m = 0; m < 4; ++m) {
      int c = wc + m*16 + l15;
      float bc = bias[c];
#pragma unroll
      for (int n = 0; n < 4; ++n) {
        int rl = rbase + n*16 + g*4;
        f32x4 v = acc[m][n];
        bf16x4 o;
#pragma unroll
        for (int j = 0; j < 4; ++j) o[j] = (bf16)fmaxf(v[j] + bc, 0.f);
        *(bf16x4*)(out + ((size_t)(b*128 + c))*512 + rl) = o;
      }
    }
  }
}

// -------------------------------------------------- adjacency softmax stats
__global__ __launch_bounds__(256) void adjstats_kernel(
    const float* __restrict__ jets, const float* __restrict__ mask,
    float* __restrict__ marr, float* __restrict__ larr) {
  __shared__ float Xs[Nn*9];
  __shared__ float cbs[Nn];
  int t = threadIdx.x;
  int b = blockIdx.x >> 4, itile = blockIdx.x & 15;
  const float* jb = jets + (size_t)b*Nn*8;
  for (int j = t; j < Nn; j += 256) {
    float s2 = 0.f;
#pragma unroll
    for (int f = 0; f < 8; ++f) { float v = jb[j*8+f]; Xs[j*9+f] = v; s2 = fmaf(v,v,s2); }
    cbs[j] = s2 + (mask[(size_t)b*Nn+j] > 0.f ? 0.f : 1e9f);
  }
  __syncthreads();
  int w = t >> 6, lane = t & 63;
  for (int rr = 0; rr < 8; ++rr) {
    int i = itile*32 + w*8 + rr;
    float xi[8];
#pragma unroll
    for (int f = 0; f < 8; ++f) xi[f] = Xs[i*9+f];
    float s[8];
#pragma unroll
    for (int q = 0; q < 8; ++q) {
      int j = lane + q*64;
      float d = 0.f;
#pragma unroll
      for (int f = 0; f < 8; ++f) d = fmaf(xi[f], Xs[j*9+f], d);
      s[q] = 2.f*d - cbs[j];
    }
    float mx = s[0];
#pragma unroll
    for (int q = 1; q < 8; ++q) mx = fmaxf(mx, s[q]);
    for (int o = 32; o; o >>= 1) mx = fmaxf(mx, __shfl_xor(mx, o, 64));
    float sum = 0.f;
#pragma unroll
    for (int q = 0; q < 8; ++q) sum += __expf(s[q]-mx);
    for (int o = 32; o; o >>= 1) sum += __shfl_xor(sum, o, 64);
    if (lane == 0) { marr[(size_t)b*Nn+i] = mx; larr[(size_t)b*Nn+i] = sum; }
  }
}

// -------------------------------------------------- agg = P @ msg  (MFMA)
__global__ __launch_bounds__(256) void agg_mfma(
    const float* __restrict__ jets, const float* __restrict__ mask,
    const float* __restrict__ marr, const float* __restrict__ larr,
    const bf16* __restrict__ msgT, bf16* __restrict__ aggb) {
  __shared__ float Xs[Nn*9];
  __shared__ float cbs[Nn];
  int t = threadIdx.x;
  int b = blockIdx.x >> 3, ic = blockIdx.x & 7;
  const float* jb = jets + (size_t)b*Nn*8;
  for (int j = t; j < Nn; j += 256) {
    float s2 = 0.f;
#pragma unroll
    for (int f = 0; f < 8; ++f) { float v = jb[j*8+f]; Xs[j*9+f] = v; s2 = fmaf(v,v,s2); }
    cbs[j] = s2 + (mask[(size_t)b*Nn+j] > 0.f ? 0.f : 1e9f);
  }
  __syncthreads();
  int w = t >> 6, lane = t & 63, l15 = lane & 15, g = lane >> 4;
  int i = ic*64 + w*16 + l15;
  float xi2[8];
#pragma unroll
  for (int f = 0; f < 8; ++f) xi2[f] = 2.f*Xs[i*9+f];
  float m_i = marr[(size_t)b*Nn+i];
  float r_i = 1.f/larr[(size_t)b*Nn+i];
  f32x4 acc[8];
#pragma unroll
  for (int m = 0; m < 8; ++m) acc[m] = (f32x4){0.f,0.f,0.f,0.f};
  const bf16* mB = msgT + (size_t)b*128*512;
#pragma unroll 2
  for (int j0 = 0; j0 < Nn; j0 += 32) {
    bf16x8 pfr;
#pragma unroll
    for (int e = 0; e < 8; ++e) {
      int j = j0 + 8*g + e;
      float d = -(cbs[j] + m_i);
#pragma unroll
      for (int f = 0; f < 8; ++f) d = fmaf(xi2[f], Xs[j*9+f], d);
      pfr[e] = (bf16)(__expf(d) * r_i);
    }
    bf16x8 afr[8];
#pragma unroll
    for (int m = 0; m < 8; ++m)
      afr[m] = *(const bf16x8*)(mB + (size_t)(m*16 + l15)*512 + j0 + 8*g);
#pragma unroll
    for (int m = 0; m < 8; ++m)
      acc[m] = __builtin_amdgcn_mfma_f32_16x16x32_bf16(afr[m], pfr, acc[m], 0,0,0);
  }
#pragma unroll
  for (int m = 0; m < 8; ++m) {
    bf16x4 o;
#pragma unroll
    for (int j = 0; j < 4; ++j) o[j] = (bf16)acc[m][j];
    *(bf16x4*)(aggb + ((size_t)b*Nn + i)*128 + m*16 + g*4) = o;
  }
}

// -------------------------------------------------- pool
__global__ __launch_bounds__(256) void pool_kernel(
    const bf16* __restrict__ h, const float* __restrict__ mask,
    float* __restrict__ pooled) {
  __shared__ float part[3][128];
  int b = blockIdx.x, t = threadIdx.x, g = t >> 6, cp = (t & 63)*2;
  float a0 = 0.f, a1 = 0.f;
  for (int n = g*128; n < g*128+128; ++n) {
    float mv = mask[(size_t)b*Nn + n];
    bf16x2 v = *(const bf16x2*)(h + ((size_t)b*Nn + n)*128 + cp);
    a0 = fmaf((float)v[0], mv, a0);
    a1 = fmaf((float)v[1], mv, a1);
  }
  if (g > 0) { part[g-1][cp] = a0; part[g-1][cp+1] = a1; }
  __syncthreads();
  if (g == 0) {
    a0 += part[0][cp] + part[1][cp] + part[2][cp];
    a1 += part[0][cp+1] + part[1][cp+1] + part[2][cp+1];
    pooled[(size_t)b*128 + cp]   = a0;
    pooled[(size_t)b*128 + cp+1] = a1;
  }
}

// -------------------------------------------------- readout (fp32)
__global__ __launch_bounds__(256) void readout_kernel(
    const float* __restrict__ pooled, const float* __restrict__ W1,
    const float* __restrict__ b1, const float* __restrict__ W2,
    const float* __restrict__ b2, float* __restrict__ out) {
  __shared__ float pl[128], hid[128];
  int b = blockIdx.x, t = threadIdx.x;   // 128 threads
  pl[t] = pooled[(size_t)b*128 + t];
  __syncthreads();
  float acc = b1[t];
#pragma unroll 4
  for (int j = 0; j < 128; ++j) acc = fmaf(pl[j], W1[j*128 + t], acc);
  hid[t] = fmaxf(acc, 0.f);
  __syncthreads();
  float acc2 = b2[t];
#pragma unroll 4
  for (int j = 0; j < 128; ++j) acc2 = fmaf(hid[j], W2[j*128 + t], acc2);
  out[(size_t)b*128 + t] = acc2;
}

// -------------------------------------------------- launch
extern "C" void kernel_launch(void* const* d_in, const int* in_sizes, int n_in,
                              void* d_out, int out_size, void* d_ws, size_t ws_size,
                              hipStream_t stream) {
  const float* jets = (const float*)d_in[0];
  const float* mask = (const float*)d_in[1];
  const float* eW0  = (const float*)d_in[2];
  const float* eb0  = (const float*)d_in[3];
  const float* eW1  = (const float*)d_in[4];
  const float* eb1  = (const float*)d_in[5];
  const float* Wm   = (const float*)d_in[6];
  const float* bm   = (const float*)d_in[7];
  const float* Wu   = (const float*)d_in[8];
  const float* bu   = (const float*)d_in[9];
  const float* rW1  = (const float*)d_in[10];
  const float* rb1  = (const float*)d_in[11];
  const float* rW2  = (const float*)d_in[12];
  const float* rb2  = (const float*)d_in[13];
  float* out = (float*)d_out;

  bf16* h    = (bf16*)d_ws;                    // ROWS*128
  bf16* msgT = h    + (size_t)ROWS*128;        // ROWS*128 (layout [b][c][n])
  bf16* aggb = msgT + (size_t)ROWS*128;        // ROWS*128 (also embed temp)
  bf16* WTe  = aggb + (size_t)ROWS*128;        // 128*128
  bf16* WTm  = WTe  + 128*128;                 // 3*128*128
  bf16* WTu  = WTm  + 3*128*128;               // 3*256*128
  float* marr   = (float*)(WTu + 3*256*128);   // ROWS
  float* larr   = marr + ROWS;                 // ROWS
  float* pooled = larr + ROWS;                 // Bb*128

  prep_wt<<<(128*128+255)/256,   256, 0, stream>>>(eW1, WTe, 128, 128*128);
  prep_wt<<<(3*128*128+255)/256, 256, 0, stream>>>(Wm,  WTm, 128, 3*128*128);
  prep_wt<<<(3*256*128+255)/256, 256, 0, stream>>>(Wu,  WTu, 256, 3*256*128);

  embed1_kernel<<<ROWS/4, 256, 0, stream>>>(jets, eW0, eb0, aggb);
  mfma_dense<128,false,false><<<ROWS/128, 256, 0, stream>>>(aggb, nullptr, WTe, eb1, nullptr, h);
  adjstats_kernel<<<Bb*(Nn/32), 256, 0, stream>>>(jets, mask, marr, larr);

  for (int it = 0; it < 3; ++it) {
    mfma_dense<128,false,true><<<ROWS/128, 256, 0, stream>>>(h, nullptr, WTm + (size_t)it*128*128, bm + it*128, nullptr, msgT);
    agg_mfma<<<Bb*(Nn/64), 256, 0, stream>>>(jets, mask, marr, larr, msgT, aggb);
    mfma_dense<256,true,false><<<ROWS/128, 256, 0, stream>>>(h, aggb, WTu + (size_t)it*256*128, bu + it*128, mask, h);
  }

  pool_kernel<<<Bb, 256, 0, stream>>>(h, mask, pooled);
  readout_kernel<<<Bb, 128, 0, stream>>>(pooled, rW1, rb1, rW2, rb2, out);
}

// Round 3
// 281.137 us; speedup vs baseline: 7.8698x; 1.3248x over previous
//
#include <hip/hip_runtime.h>
#include <stdint.h>
#include <stddef.h>

#define Bb 128
#define Nn 512
#define Hh 128
#define ROWS (Bb*Nn)

typedef __bf16 bf16;
typedef __bf16 bf16x2 __attribute__((ext_vector_type(2)));
typedef __bf16 bf16x4 __attribute__((ext_vector_type(4)));
typedef __bf16 bf16x8 __attribute__((ext_vector_type(8)));
typedef float  f32x4  __attribute__((ext_vector_type(4)));

__device__ __forceinline__ void glds16(const void* g, void* l) {
  __builtin_amdgcn_global_load_lds(
      (const __attribute__((address_space(1))) void*)g,
      (__attribute__((address_space(3))) void*)l, 16, 0, 0);
}

// -------------------------------------------------- weight prep: fp32 W[k][c]
// -> bf16 W^T[c][k] with XOR swizzle (k ^ ((c&7)<<3)) pre-applied so the dense
// kernel can stage linearly via global_load_lds and ds_read_b128 conflict-free.
__global__ __launch_bounds__(256) void prep_wt(const float* __restrict__ src,
                                               bf16* __restrict__ dst,
                                               int K, int total) {
  int idx = blockIdx.x*256 + threadIdx.x;
  if (idx >= total) return;
  int mk = K*128;
  int m = idx / mk, rem = idx - m*mk;
  int k = rem >> 7, c = rem & 127;
  dst[m*mk + c*K + (k ^ ((c & 7) << 3))] = (bf16)src[idx];
}

// -------------------------------------------------- embed layer 1 (K=8, VALU)
__global__ __launch_bounds__(256) void embed1_kernel(
    const float* __restrict__ jets, const float* __restrict__ W0,
    const float* __restrict__ b0, bf16* __restrict__ out) {
  __shared__ float sW[8*128];
  __shared__ float sb[128];
  int t = threadIdx.x;
  for (int i = t; i < 8*128; i += 256) sW[i] = W0[i];
  if (t < 128) sb[t] = b0[t];
  __syncthreads();
  int row = blockIdx.x*4 + (t >> 6);
  int cp  = (t & 63)*2;
  const float* x = jets + (size_t)row*8;
  float a0 = sb[cp], a1 = sb[cp+1];
#pragma unroll
  for (int f = 0; f < 8; ++f) {
    float xv = x[f];
    a0 = fmaf(xv, sW[f*128+cp],   a0);
    a1 = fmaf(xv, sW[f*128+cp+1], a1);
  }
  bf16x2 o; o[0] = (bf16)fmaxf(a0,0.f); o[1] = (bf16)fmaxf(a1,0.f);
  *(bf16x2*)(out + (size_t)row*128 + cp) = o;
}

// -------------------------------------------------- MFMA dense
// out = relu(A @ W + b) [*mask].  A = A0 (k<128) / A1 (k>=128), bf16 row-major.
// W^T bf16 swizzled resident in LDS. Block: 128 rows x 128 cols, 4 waves 2x2.
// TRANSOUT=0: mfma(Wfrag, Afrag) -> lane holds 4 consecutive cols -> row-major out.
// TRANSOUT=1: mfma(Afrag, Wfrag) -> lane holds 4 consecutive rows -> writes msgT[c][r].
template<int K, bool MASKMUL, bool TRANSOUT>
__global__ __launch_bounds__(256) void mfma_dense(
    const bf16* __restrict__ A0, const bf16* __restrict__ A1,
    const bf16* __restrict__ WT, const float* __restrict__ bias,
    const float* __restrict__ mask, bf16* __restrict__ out) {
  __shared__ bf16 sWT[128*K];
  const int t = threadIdx.x;
  const int w = t >> 6, lane = t & 63;
  const int l15 = lane & 15, g = lane >> 4;
  const int CH = (128*K*2)/1024;          // 1 KB per wave-instr
  for (int q = w; q < CH; q += 4)
    glds16((const char*)WT + q*1024 + lane*16, (char*)(void*)sWT + q*1024);

  const int row_blk = blockIdx.x*128;
  const int wr = (w & 1)*64, wc = (w >> 1)*64;
  int rowg[4];
#pragma unroll
  for (int n = 0; n < 4; ++n) rowg[n] = row_blk + wr + n*16 + l15;
  f32x4 acc[4][4];
#pragma unroll
  for (int m = 0; m < 4; ++m)
#pragma unroll
    for (int n = 0; n < 4; ++n) acc[m][n] = (f32x4){0.f,0.f,0.f,0.f};
  __syncthreads();

#pragma unroll
  for (int kk = 0; kk < K; kk += 32) {
    const bf16* base; int kl;
    if (K == 128) { base = A0; kl = kk; }
    else          { base = (kk < 128) ? A0 : A1; kl = kk & 127; }
    bf16x8 bfr[4];
#pragma unroll
    for (int n = 0; n < 4; ++n)
      bfr[n] = *(const bf16x8*)(base + (size_t)rowg[n]*128 + kl + 8*g);
    bf16x8 wfr[4];
#pragma unroll
    for (int m = 0; m < 4; ++m) {
      int c = wc + m*16 + l15;
      int kidx = (kk + 8*g) ^ ((c & 7) << 3);
      wfr[m] = *(const bf16x8*)(sWT + c*K + kidx);
    }
#pragma unroll
    for (int m = 0; m < 4; ++m)
#pragma unroll
      for (int n = 0; n < 4; ++n) {
        if (TRANSOUT)
          acc[m][n] = __builtin_amdgcn_mfma_f32_16x16x32_bf16(bfr[n], wfr[m], acc[m][n], 0,0,0);
        else
          acc[m][n] = __builtin_amdgcn_mfma_f32_16x16x32_bf16(wfr[m], bfr[n], acc[m][n], 0,0,0);
      }
  }

  if (!TRANSOUT) {
#pragma unroll
    for (int m = 0; m < 4; ++m) {
      f32x4 bs = *(const f32x4*)(bias + wc + m*16 + g*4);
#pragma unroll
      for (int n = 0; n < 4; ++n) {
        int r = rowg[n];
        float mv = MASKMUL ? mask[r] : 1.f;
        f32x4 v = acc[m][n];
        bf16x4 o;
#pragma unroll
        for (int j = 0; j < 4; ++j) {
          float x = fmaxf(v[j] + bs[j], 0.f);
          if (MASKMUL) x *= mv;
          o[j] = (bf16)x;
        }
        *(bf16x4*)(out + (size_t)r*128 + wc + m*16 + g*4) = o;
      }
    }
  } else {
    const int b = row_blk >> 9;
    const int rbase = (row_blk & 511) + wr;
#pragma unroll
    for (int m = 0; m < 4; ++m) {
      int c = wc + m*16 + l15;
      float bc = bias[c];
#pragma unroll
      for (int n = 0; n < 4; ++n) {
        int rl = rbase + n*16 + g*4;
        f32x4 v = acc[m][n];
        bf16x4 o;
#pragma unroll
        for (int j = 0; j < 4; ++j) o[j] = (bf16)fmaxf(v[j] + bc, 0.f);
        *(bf16x4*)(out + ((size_t)(b*128 + c))*512 + rl) = o;
      }
    }
  }
}

// -------------------------------------------------- adjacency softmax stats
__global__ __launch_bounds__(256) void adjstats_kernel(
    const float* __restrict__ jets, const float* __restrict__ mask,
    float* __restrict__ marr, float* __restrict__ larr) {
  __shared__ float Xs[Nn*9];
  __shared__ float cbs[Nn];
  int t = threadIdx.x;
  int b = blockIdx.x >> 4, itile = blockIdx.x & 15;
  const float* jb = jets + (size_t)b*Nn*8;
  for (int j = t; j < Nn; j += 256) {
    float s2 = 0.f;
#pragma unroll
    for (int f = 0; f < 8; ++f) { float v = jb[j*8+f]; Xs[j*9+f] = v; s2 = fmaf(v,v,s2); }
    cbs[j] = s2 + (mask[(size_t)b*Nn+j] > 0.f ? 0.f : 1e9f);
  }
  __syncthreads();
  int w = t >> 6, lane = t & 63;
  for (int rr = 0; rr < 8; ++rr) {
    int i = itile*32 + w*8 + rr;
    float xi[8];
#pragma unroll
    for (int f = 0; f < 8; ++f) xi[f] = Xs[i*9+f];
    float s[8];
#pragma unroll
    for (int q = 0; q < 8; ++q) {
      int j = lane + q*64;
      float d = 0.f;
#pragma unroll
      for (int f = 0; f < 8; ++f) d = fmaf(xi[f], Xs[j*9+f], d);
      s[q] = 2.f*d - cbs[j];
    }
    float mx = s[0];
#pragma unroll
    for (int q = 1; q < 8; ++q) mx = fmaxf(mx, s[q]);
    for (int o = 32; o; o >>= 1) mx = fmaxf(mx, __shfl_xor(mx, o, 64));
    float sum = 0.f;
#pragma unroll
    for (int q = 0; q < 8; ++q) sum += __expf(s[q]-mx);
    for (int o = 32; o; o >>= 1) sum += __shfl_xor(sum, o, 64);
    if (lane == 0) { marr[(size_t)b*Nn+i] = mx; larr[(size_t)b*Nn+i] = sum; }
  }
}

// -------------------------------------------------- agg = P @ msg  (MFMA)
// XCD-aware decode: b = wgid & 127 -> all i-chunks of a batch share wgid%8,
// i.e. the same XCD; msgT batch slice (131 KB) stays L2-resident.
// Block: 128 i-rows (4 waves x 32 rows); wave: 2 row-tiles x 8 col-tiles.
__global__ __launch_bounds__(256) void agg_mfma(
    const float* __restrict__ jets, const float* __restrict__ mask,
    const float* __restrict__ marr, const float* __restrict__ larr,
    const bf16* __restrict__ msgT, bf16* __restrict__ aggb) {
  __shared__ float Xs[Nn*9];
  __shared__ float cbs[Nn];
  int t = threadIdx.x;
  int b  = blockIdx.x & 127;
  int ic = blockIdx.x >> 7;          // 0..3
  const float* jb = jets + (size_t)b*Nn*8;
  for (int j = t; j < Nn; j += 256) {
    float s2 = 0.f;
#pragma unroll
    for (int f = 0; f < 8; ++f) { float v = jb[j*8+f]; Xs[j*9+f] = v; s2 = fmaf(v,v,s2); }
    cbs[j] = s2 + (mask[(size_t)b*Nn+j] > 0.f ? 0.f : 1e9f);
  }
  __syncthreads();
  int w = t >> 6, lane = t & 63, l15 = lane & 15, g = lane >> 4;
  int i0 = ic*128 + w*32;            // wave's 32 rows
  float xi2[2][8];
  float m_i[2], r_i[2];
#pragma unroll
  for (int r = 0; r < 2; ++r) {
    int i = i0 + r*16 + l15;
#pragma unroll
    for (int f = 0; f < 8; ++f) xi2[r][f] = 2.f*Xs[i*9+f];
    m_i[r] = marr[(size_t)b*Nn+i];
    r_i[r] = 1.f/larr[(size_t)b*Nn+i];
  }
  f32x4 acc[2][8];
#pragma unroll
  for (int r = 0; r < 2; ++r)
#pragma unroll
    for (int m = 0; m < 8; ++m) acc[r][m] = (f32x4){0.f,0.f,0.f,0.f};
  const bf16* mB = msgT + (size_t)b*128*512;
#pragma unroll 2
  for (int j0 = 0; j0 < Nn; j0 += 32) {
    bf16x8 pfr[2];
#pragma unroll
    for (int r = 0; r < 2; ++r)
#pragma unroll
      for (int e = 0; e < 8; ++e) {
        int j = j0 + 8*g + e;
        float d = -(cbs[j] + m_i[r]);
#pragma unroll
        for (int f = 0; f < 8; ++f) d = fmaf(xi2[r][f], Xs[j*9+f], d);
        pfr[r][e] = (bf16)(__expf(d) * r_i[r]);
      }
    bf16x8 afr[8];
#pragma unroll
    for (int m = 0; m < 8; ++m)
      afr[m] = *(const bf16x8*)(mB + (size_t)(m*16 + l15)*512 + j0 + 8*g);
#pragma unroll
    for (int m = 0; m < 8; ++m)
#pragma unroll
      for (int r = 0; r < 2; ++r)
        acc[r][m] = __builtin_amdgcn_mfma_f32_16x16x32_bf16(afr[m], pfr[r], acc[r][m], 0,0,0);
  }
#pragma unroll
  for (int r = 0; r < 2; ++r) {
    int i = i0 + r*16 + l15;
#pragma unroll
    for (int m = 0; m < 8; ++m) {
      bf16x4 o;
#pragma unroll
      for (int j = 0; j < 4; ++j) o[j] = (bf16)acc[r][m][j];
      *(bf16x4*)(aggb + ((size_t)b*Nn + i)*128 + m*16 + g*4) = o;
    }
  }
}

// -------------------------------------------------- pool
__global__ __launch_bounds__(256) void pool_kernel(
    const bf16* __restrict__ h, const float* __restrict__ mask,
    float* __restrict__ pooled) {
  __shared__ float part[3][128];
  int b = blockIdx.x, t = threadIdx.x, g = t >> 6, cp = (t & 63)*2;
  float a0 = 0.f, a1 = 0.f;
  for (int n = g*128; n < g*128+128; ++n) {
    float mv = mask[(size_t)b*Nn + n];
    bf16x2 v = *(const bf16x2*)(h + ((size_t)b*Nn + n)*128 + cp);
    a0 = fmaf((float)v[0], mv, a0);
    a1 = fmaf((float)v[1], mv, a1);
  }
  if (g > 0) { part[g-1][cp] = a0; part[g-1][cp+1] = a1; }
  __syncthreads();
  if (g == 0) {
    a0 += part[0][cp] + part[1][cp] + part[2][cp];
    a1 += part[0][cp+1] + part[1][cp+1] + part[2][cp+1];
    pooled[(size_t)b*128 + cp]   = a0;
    pooled[(size_t)b*128 + cp+1] = a1;
  }
}

// -------------------------------------------------- readout (fp32)
__global__ __launch_bounds__(256) void readout_kernel(
    const float* __restrict__ pooled, const float* __restrict__ W1,
    const float* __restrict__ b1, const float* __restrict__ W2,
    const float* __restrict__ b2, float* __restrict__ out) {
  __shared__ float pl[128], hid[128];
  int b = blockIdx.x, t = threadIdx.x;   // 128 threads
  pl[t] = pooled[(size_t)b*128 + t];
  __syncthreads();
  float acc = b1[t];
#pragma unroll 4
  for (int j = 0; j < 128; ++j) acc = fmaf(pl[j], W1[j*128 + t], acc);
  hid[t] = fmaxf(acc, 0.f);
  __syncthreads();
  float acc2 = b2[t];
#pragma unroll 4
  for (int j = 0; j < 128; ++j) acc2 = fmaf(hid[j], W2[j*128 + t], acc2);
  out[(size_t)b*128 + t] = acc2;
}

// -------------------------------------------------- launch
extern "C" void kernel_launch(void* const* d_in, const int* in_sizes, int n_in,
                              void* d_out, int out_size, void* d_ws, size_t ws_size,
                              hipStream_t stream) {
  const float* jets = (const float*)d_in[0];
  const float* mask = (const float*)d_in[1];
  const float* eW0  = (const float*)d_in[2];
  const float* eb0  = (const float*)d_in[3];
  const float* eW1  = (const float*)d_in[4];
  const float* eb1  = (const float*)d_in[5];
  const float* Wm   = (const float*)d_in[6];
  const float* bm   = (const float*)d_in[7];
  const float* Wu   = (const float*)d_in[8];
  const float* bu   = (const float*)d_in[9];
  const float* rW1  = (const float*)d_in[10];
  const float* rb1  = (const float*)d_in[11];
  const float* rW2  = (const float*)d_in[12];
  const float* rb2  = (const float*)d_in[13];
  float* out = (float*)d_out;

  bf16* h    = (bf16*)d_ws;                    // ROWS*128
  bf16* msgT = h    + (size_t)ROWS*128;        // ROWS*128 (layout [b][c][n])
  bf16* aggb = msgT + (size_t)ROWS*128;        // ROWS*128 (also embed temp)
  bf16* WTe  = aggb + (size_t)ROWS*128;        // 128*128
  bf16* WTm  = WTe  + 128*128;                 // 3*128*128
  bf16* WTu  = WTm  + 3*128*128;               // 3*256*128
  float* marr   = (float*)(WTu + 3*256*128);   // ROWS
  float* larr   = marr + ROWS;                 // ROWS
  float* pooled = larr + ROWS;                 // Bb*128

  prep_wt<<<(128*128+255)/256,   256, 0, stream>>>(eW1, WTe, 128, 128*128);
  prep_wt<<<(3*128*128+255)/256, 256, 0, stream>>>(Wm,  WTm, 128, 3*128*128);
  prep_wt<<<(3*256*128+255)/256, 256, 0, stream>>>(Wu,  WTu, 256, 3*256*128);

  embed1_kernel<<<ROWS/4, 256, 0, stream>>>(jets, eW0, eb0, aggb);
  mfma_dense<128,false,false><<<ROWS/128, 256, 0, stream>>>(aggb, nullptr, WTe, eb1, nullptr, h);
  adjstats_kernel<<<Bb*(Nn/32), 256, 0, stream>>>(jets, mask, marr, larr);

  for (int it = 0; it < 3; ++it) {
    mfma_dense<128,false,true><<<ROWS/128, 256, 0, stream>>>(h, nullptr, WTm + (size_t)it*128*128, bm + it*128, nullptr, msgT);
    agg_mfma<<<Bb*4, 256, 0, stream>>>(jets, mask, marr, larr, msgT, aggb);
    mfma_dense<256,true,false><<<ROWS/128, 256, 0, stream>>>(h, aggb, WTu + (size_t)it*256*128, bu + it*128, mask, h);
  }

  pool_kernel<<<Bb, 256, 0, stream>>>(h, mask, pooled);
  readout_kernel<<<Bb, 128, 0, stream>>>(pooled, rW1, rb1, rW2, rb2, out);
}

// Round 4
// 250.583 us; speedup vs baseline: 8.8294x; 1.1219x over previous
//
#include <hip/hip_runtime.h>
#include <stdint.h>
#include <stddef.h>

#define Bb 128
#define Nn 512
#define Hh 128
#define ROWS (Bb*Nn)

typedef __bf16 bf16;
typedef __bf16 bf16x2 __attribute__((ext_vector_type(2)));
typedef __bf16 bf16x4 __attribute__((ext_vector_type(4)));
typedef __bf16 bf16x8 __attribute__((ext_vector_type(8)));
typedef float  f32x4  __attribute__((ext_vector_type(4)));

__device__ __forceinline__ void glds16(const void* g, void* l) {
  __builtin_amdgcn_global_load_lds(
      (const __attribute__((address_space(1))) void*)g,
      (__attribute__((address_space(3))) void*)l, 16, 0, 0);
}

// -------------------------------------------------- weight prep (all in one)
// fp32 W[k][c] -> bf16 W^T[c][k ^ ((c&7)<<3)]  (swizzle pre-applied)
__global__ __launch_bounds__(256) void prep_all(
    const float* __restrict__ eW1, const float* __restrict__ Wm,
    const float* __restrict__ Wu, bf16* __restrict__ WTe,
    bf16* __restrict__ WTm, bf16* __restrict__ WTu) {
  int idx = blockIdx.x*256 + threadIdx.x;
  if (idx < 16384) {                       // eW1: 128x128
    int k = idx >> 7, c = idx & 127;
    WTe[c*128 + (k ^ ((c & 7) << 3))] = (bf16)eW1[idx];
  } else if (idx < 16384 + 49152) {        // Wm: 3x128x128
    int sub = idx - 16384;
    int m = sub >> 14, r = sub & 16383;
    int k = r >> 7, c = r & 127;
    WTm[m*16384 + c*128 + (k ^ ((c & 7) << 3))] = (bf16)Wm[sub];
  } else if (idx < 16384 + 49152 + 98304) { // Wu: 3x256x128
    int sub = idx - 65536;
    int m = sub >> 15, r = sub & 32767;
    int k = r >> 7, c = r & 127;
    WTu[m*32768 + c*256 + (k ^ ((c & 7) << 3))] = (bf16)Wu[sub];
  }
}

// -------------------------------------------------- fused embed (L1 VALU + L2 MFMA)
// h = relu(relu(jets@W0+b0)@W1 + b1); 128 rows/block.
__global__ __launch_bounds__(256) void embed_fused(
    const float* __restrict__ jets, const float* __restrict__ W0,
    const float* __restrict__ b0, const bf16* __restrict__ WTe,
    const float* __restrict__ b1, bf16* __restrict__ h) {
  __shared__ float sW0[8*128];
  __shared__ float sb0[128];
  __shared__ bf16 h0s[128*128];   // swizzled
  __shared__ bf16 sWT[128*128];   // swizzled W1^T
  const int t = threadIdx.x;
  const int w = t >> 6, lane = t & 63, l15 = lane & 15, g = lane >> 4;
  // stage W1^T via async LDS, W0/b0 via VALU
  for (int q = w; q < 32; q += 4)
    glds16((const char*)WTe + q*1024 + lane*16, (char*)(void*)sWT + q*1024);
  for (int i = t; i < 8*128; i += 256) sW0[i] = W0[i];
  if (t < 128) sb0[t] = b0[t];
  __syncthreads();
  // layer 1: thread owns 1 row, 64 cols
  {
    const int row = t & 127, colbase = (t >> 7) * 64;
    const float4* jp = (const float4*)(jets + ((size_t)blockIdx.x*128 + row)*8);
    float4 x0 = jp[0], x1 = jp[1];
    float x[8] = {x0.x,x0.y,x0.z,x0.w,x1.x,x1.y,x1.z,x1.w};
    const int sw = (row & 7) << 3;
#pragma unroll
    for (int cg = 0; cg < 16; ++cg) {
      int c0 = colbase + cg*4;
      bf16x4 o;
#pragma unroll
      for (int j = 0; j < 4; ++j) {
        float a = sb0[c0+j];
#pragma unroll
        for (int f = 0; f < 8; ++f) a = fmaf(x[f], sW0[f*128 + c0 + j], a);
        o[j] = (bf16)fmaxf(a, 0.f);
      }
      *(bf16x4*)(h0s + row*128 + (c0 ^ sw)) = o;
    }
  }
  __syncthreads();
  // layer 2: MFMA, 4 waves 2x2
  const int wr = (w & 1)*64, wc = (w >> 1)*64;
  f32x4 acc[4][4];
#pragma unroll
  for (int m = 0; m < 4; ++m)
#pragma unroll
    for (int n = 0; n < 4; ++n) acc[m][n] = (f32x4){0.f,0.f,0.f,0.f};
#pragma unroll
  for (int kk = 0; kk < 128; kk += 32) {
    bf16x8 bfr[4], wfr[4];
#pragma unroll
    for (int n = 0; n < 4; ++n) {
      int row = wr + n*16 + l15;
      bfr[n] = *(const bf16x8*)(h0s + row*128 + ((kk + 8*g) ^ ((row & 7) << 3)));
    }
#pragma unroll
    for (int m = 0; m < 4; ++m) {
      int c = wc + m*16 + l15;
      wfr[m] = *(const bf16x8*)(sWT + c*128 + ((kk + 8*g) ^ ((c & 7) << 3)));
    }
#pragma unroll
    for (int m = 0; m < 4; ++m)
#pragma unroll
      for (int n = 0; n < 4; ++n)
        acc[m][n] = __builtin_amdgcn_mfma_f32_16x16x32_bf16(wfr[m], bfr[n], acc[m][n], 0,0,0);
  }
#pragma unroll
  for (int m = 0; m < 4; ++m) {
    f32x4 bs = *(const f32x4*)(b1 + wc + m*16 + g*4);
#pragma unroll
    for (int n = 0; n < 4; ++n) {
      int r = blockIdx.x*128 + wr + n*16 + l15;
      bf16x4 o;
#pragma unroll
      for (int j = 0; j < 4; ++j) o[j] = (bf16)fmaxf(acc[m][n][j] + bs[j], 0.f);
      *(bf16x4*)(h + (size_t)r*128 + wc + m*16 + g*4) = o;
    }
  }
}

// -------------------------------------------------- MFMA dense (msg0 / last update)
template<int K, bool MASKMUL, bool TRANSOUT>
__global__ __launch_bounds__(256) void mfma_dense(
    const bf16* __restrict__ A0, const bf16* __restrict__ A1,
    const bf16* __restrict__ WT, const float* __restrict__ bias,
    const float* __restrict__ mask, bf16* __restrict__ out) {
  __shared__ bf16 sWT[128*K];
  const int t = threadIdx.x;
  const int w = t >> 6, lane = t & 63;
  const int l15 = lane & 15, g = lane >> 4;
  const int CH = (128*K*2)/1024;
  for (int q = w; q < CH; q += 4)
    glds16((const char*)WT + q*1024 + lane*16, (char*)(void*)sWT + q*1024);

  const int row_blk = blockIdx.x*128;
  const int wr = (w & 1)*64, wc = (w >> 1)*64;
  int rowg[4];
#pragma unroll
  for (int n = 0; n < 4; ++n) rowg[n] = row_blk + wr + n*16 + l15;
  f32x4 acc[4][4];
#pragma unroll
  for (int m = 0; m < 4; ++m)
#pragma unroll
    for (int n = 0; n < 4; ++n) acc[m][n] = (f32x4){0.f,0.f,0.f,0.f};
  __syncthreads();

#pragma unroll
  for (int kk = 0; kk < K; kk += 32) {
    const bf16* base; int kl;
    if (K == 128) { base = A0; kl = kk; }
    else          { base = (kk < 128) ? A0 : A1; kl = kk & 127; }
    bf16x8 bfr[4];
#pragma unroll
    for (int n = 0; n < 4; ++n)
      bfr[n] = *(const bf16x8*)(base + (size_t)rowg[n]*128 + kl + 8*g);
    bf16x8 wfr[4];
#pragma unroll
    for (int m = 0; m < 4; ++m) {
      int c = wc + m*16 + l15;
      int kidx = (kk + 8*g) ^ ((c & 7) << 3);
      wfr[m] = *(const bf16x8*)(sWT + c*K + kidx);
    }
#pragma unroll
    for (int m = 0; m < 4; ++m)
#pragma unroll
      for (int n = 0; n < 4; ++n) {
        if (TRANSOUT)
          acc[m][n] = __builtin_amdgcn_mfma_f32_16x16x32_bf16(bfr[n], wfr[m], acc[m][n], 0,0,0);
        else
          acc[m][n] = __builtin_amdgcn_mfma_f32_16x16x32_bf16(wfr[m], bfr[n], acc[m][n], 0,0,0);
      }
  }

  if (!TRANSOUT) {
#pragma unroll
    for (int m = 0; m < 4; ++m) {
      f32x4 bs = *(const f32x4*)(bias + wc + m*16 + g*4);
#pragma unroll
      for (int n = 0; n < 4; ++n) {
        int r = rowg[n];
        float mv = MASKMUL ? mask[r] : 1.f;
        f32x4 v = acc[m][n];
        bf16x4 o;
#pragma unroll
        for (int j = 0; j < 4; ++j) {
          float x = fmaxf(v[j] + bs[j], 0.f);
          if (MASKMUL) x *= mv;
          o[j] = (bf16)x;
        }
        *(bf16x4*)(out + (size_t)r*128 + wc + m*16 + g*4) = o;
      }
    }
  } else {
    const int b = row_blk >> 9;
    const int rbase = (row_blk & 511) + wr;
#pragma unroll
    for (int m = 0; m < 4; ++m) {
      int c = wc + m*16 + l15;
      float bc = bias[c];
#pragma unroll
      for (int n = 0; n < 4; ++n) {
        int rl = rbase + n*16 + g*4;
        f32x4 v = acc[m][n];
        bf16x4 o;
#pragma unroll
        for (int j = 0; j < 4; ++j) o[j] = (bf16)fmaxf(v[j] + bc, 0.f);
        *(bf16x4*)(out + ((size_t)(b*128 + c))*512 + rl) = o;
      }
    }
  }
}

// -------------------------------------------------- fused update + msg
// GEMM1: h_new = relu([h,agg]@Wu + bu)*mask (K=256), staged to LDS + global h.
// GEMM2: msgT = relu(h_new@Wm + bm) (K=128, TRANSOUT), Wm frags from L2.
// 512 threads, 256 rows/block, 256 blocks (1/CU). LDS: 64KB Wu^T + 64KB h tile.
__global__ __launch_bounds__(512) void fused_upd_msg(
    const bf16* __restrict__ h, const bf16* __restrict__ aggb,
    const bf16* __restrict__ WTu, const float* __restrict__ bu,
    const bf16* __restrict__ WTm, const float* __restrict__ bm,
    const float* __restrict__ mask, bf16* __restrict__ hout,
    bf16* __restrict__ msgT) {
  __shared__ bf16 sWTu[128*256];
  __shared__ bf16 htile[256*128];  // swizzled
  const int t = threadIdx.x;
  const int w = t >> 6, lane = t & 63, l15 = lane & 15, g = lane >> 4;
  for (int q = w; q < 64; q += 8)
    glds16((const char*)WTu + q*1024 + lane*16, (char*)(void*)sWTu + q*1024);

  const int row_blk = blockIdx.x*256;
  // ---- GEMM1: 8 waves = 4 row-groups x 2 col-groups
  {
    const int wr = (w & 3)*64, wc = (w >> 2)*64;
    int rowg[4];
#pragma unroll
    for (int n = 0; n < 4; ++n) rowg[n] = row_blk + wr + n*16 + l15;
    f32x4 acc[4][4];
#pragma unroll
    for (int m = 0; m < 4; ++m)
#pragma unroll
      for (int n = 0; n < 4; ++n) acc[m][n] = (f32x4){0.f,0.f,0.f,0.f};
    __syncthreads();
#pragma unroll
    for (int kk = 0; kk < 256; kk += 32) {
      const bf16* base = (kk < 128) ? h : aggb;
      int kl = kk & 127;
      bf16x8 bfr[4];
#pragma unroll
      for (int n = 0; n < 4; ++n)
        bfr[n] = *(const bf16x8*)(base + (size_t)rowg[n]*128 + kl + 8*g);
      bf16x8 wfr[4];
#pragma unroll
      for (int m = 0; m < 4; ++m) {
        int c = wc + m*16 + l15;
        wfr[m] = *(const bf16x8*)(sWTu + c*256 + ((kk + 8*g) ^ ((c & 7) << 3)));
      }
#pragma unroll
      for (int m = 0; m < 4; ++m)
#pragma unroll
        for (int n = 0; n < 4; ++n)
          acc[m][n] = __builtin_amdgcn_mfma_f32_16x16x32_bf16(wfr[m], bfr[n], acc[m][n], 0,0,0);
    }
#pragma unroll
    for (int m = 0; m < 4; ++m) {
      f32x4 bs = *(const f32x4*)(bu + wc + m*16 + g*4);
#pragma unroll
      for (int n = 0; n < 4; ++n) {
        int r = rowg[n];
        int lr = wr + n*16 + l15;
        float mv = mask[r];
        bf16x4 o;
#pragma unroll
        for (int j = 0; j < 4; ++j)
          o[j] = (bf16)(fmaxf(acc[m][n][j] + bs[j], 0.f) * mv);
        int c0 = wc + m*16 + g*4;
        *(bf16x4*)(hout + (size_t)r*128 + c0) = o;
        *(bf16x4*)(htile + lr*128 + (c0 ^ ((lr & 7) << 3))) = o;
      }
    }
  }
  __syncthreads();
  // ---- GEMM2: msgT = relu(htile @ Wm + bm), TRANSOUT; 4 row-grp x 2 col-grp
  {
    const int wr = (w & 3)*64, wc = (w >> 2)*64;
    f32x4 acc[4][4];
#pragma unroll
    for (int m = 0; m < 4; ++m)
#pragma unroll
      for (int n = 0; n < 4; ++n) acc[m][n] = (f32x4){0.f,0.f,0.f,0.f};
#pragma unroll
    for (int kk = 0; kk < 128; kk += 32) {
      bf16x8 bfr[4], wfr[4];
#pragma unroll
      for (int n = 0; n < 4; ++n) {
        int lr = wr + n*16 + l15;
        bfr[n] = *(const bf16x8*)(htile + lr*128 + ((kk + 8*g) ^ ((lr & 7) << 3)));
      }
#pragma unroll
      for (int m = 0; m < 4; ++m) {
        int c = wc + m*16 + l15;
        wfr[m] = *(const bf16x8*)(WTm + c*128 + ((kk + 8*g) ^ ((c & 7) << 3)));
      }
#pragma unroll
      for (int m = 0; m < 4; ++m)
#pragma unroll
        for (int n = 0; n < 4; ++n)
          acc[m][n] = __builtin_amdgcn_mfma_f32_16x16x32_bf16(bfr[n], wfr[m], acc[m][n], 0,0,0);
    }
    const int b = row_blk >> 9;
    const int rbase = (row_blk & 511) + wr;
#pragma unroll
    for (int m = 0; m < 4; ++m) {
      int c = wc + m*16 + l15;
      float bc = bm[c];
#pragma unroll
      for (int n = 0; n < 4; ++n) {
        int rl = rbase + n*16 + g*4;
        bf16x4 o;
#pragma unroll
        for (int j = 0; j < 4; ++j) o[j] = (bf16)fmaxf(acc[m][n][j] + bc, 0.f);
        *(bf16x4*)(msgT + ((size_t)(b*128 + c))*512 + rl) = o;
      }
    }
  }
}

// -------------------------------------------------- adjacency softmax stats
__global__ __launch_bounds__(256) void adjstats_kernel(
    const float* __restrict__ jets, const float* __restrict__ mask,
    float* __restrict__ marr, float* __restrict__ larr) {
  __shared__ float Xs[Nn*9];
  __shared__ float cbs[Nn];
  int t = threadIdx.x;
  int b = blockIdx.x >> 4, itile = blockIdx.x & 15;
  const float* jb = jets + (size_t)b*Nn*8;
  for (int j = t; j < Nn; j += 256) {
    float s2 = 0.f;
#pragma unroll
    for (int f = 0; f < 8; ++f) { float v = jb[j*8+f]; Xs[j*9+f] = v; s2 = fmaf(v,v,s2); }
    cbs[j] = s2 + (mask[(size_t)b*Nn+j] > 0.f ? 0.f : 1e9f);
  }
  __syncthreads();
  int w = t >> 6, lane = t & 63;
  for (int rr = 0; rr < 8; ++rr) {
    int i = itile*32 + w*8 + rr;
    float xi[8];
#pragma unroll
    for (int f = 0; f < 8; ++f) xi[f] = Xs[i*9+f];
    float s[8];
#pragma unroll
    for (int q = 0; q < 8; ++q) {
      int j = lane + q*64;
      float d = 0.f;
#pragma unroll
      for (int f = 0; f < 8; ++f) d = fmaf(xi[f], Xs[j*9+f], d);
      s[q] = 2.f*d - cbs[j];
    }
    float mx = s[0];
#pragma unroll
    for (int q = 1; q < 8; ++q) mx = fmaxf(mx, s[q]);
    for (int o = 32; o; o >>= 1) mx = fmaxf(mx, __shfl_xor(mx, o, 64));
    float sum = 0.f;
#pragma unroll
    for (int q = 0; q < 8; ++q) sum += __expf(s[q]-mx);
    for (int o = 32; o; o >>= 1) sum += __shfl_xor(sum, o, 64);
    if (lane == 0) { marr[(size_t)b*Nn+i] = mx; larr[(size_t)b*Nn+i] = sum; }
  }
}

// -------------------------------------------------- agg = P @ msg  (MFMA)
// XCD-aware: b = wgid & 127 keeps a batch's blocks on one XCD (L2-resident msgT).
__global__ __launch_bounds__(256) void agg_mfma(
    const float* __restrict__ jets, const float* __restrict__ mask,
    const float* __restrict__ marr, const float* __restrict__ larr,
    const bf16* __restrict__ msgT, bf16* __restrict__ aggb) {
  __shared__ float Xs[Nn*9];
  __shared__ float cbs[Nn];
  int t = threadIdx.x;
  int b  = blockIdx.x & 127;
  int ic = blockIdx.x >> 7;
  const float* jb = jets + (size_t)b*Nn*8;
  for (int j = t; j < Nn; j += 256) {
    float s2 = 0.f;
#pragma unroll
    for (int f = 0; f < 8; ++f) { float v = jb[j*8+f]; Xs[j*9+f] = v; s2 = fmaf(v,v,s2); }
    cbs[j] = s2 + (mask[(size_t)b*Nn+j] > 0.f ? 0.f : 1e9f);
  }
  __syncthreads();
  int w = t >> 6, lane = t & 63, l15 = lane & 15, g = lane >> 4;
  int i0 = ic*128 + w*32;
  float xi2[2][8];
  float m_i[2], r_i[2];
#pragma unroll
  for (int r = 0; r < 2; ++r) {
    int i = i0 + r*16 + l15;
#pragma unroll
    for (int f = 0; f < 8; ++f) xi2[r][f] = 2.f*Xs[i*9+f];
    m_i[r] = marr[(size_t)b*Nn+i];
    r_i[r] = 1.f/larr[(size_t)b*Nn+i];
  }
  f32x4 acc[2][8];
#pragma unroll
  for (int r = 0; r < 2; ++r)
#pragma unroll
    for (int m = 0; m < 8; ++m) acc[r][m] = (f32x4){0.f,0.f,0.f,0.f};
  const bf16* mB = msgT + (size_t)b*128*512;
#pragma unroll 2
  for (int j0 = 0; j0 < Nn; j0 += 32) {
    bf16x8 pfr[2];
#pragma unroll
    for (int r = 0; r < 2; ++r)
#pragma unroll
      for (int e = 0; e < 8; ++e) {
        int j = j0 + 8*g + e;
        float d = -(cbs[j] + m_i[r]);
#pragma unroll
        for (int f = 0; f < 8; ++f) d = fmaf(xi2[r][f], Xs[j*9+f], d);
        pfr[r][e] = (bf16)__expf(d);
      }
    bf16x8 afr[8];
#pragma unroll
    for (int m = 0; m < 8; ++m)
      afr[m] = *(const bf16x8*)(mB + (size_t)(m*16 + l15)*512 + j0 + 8*g);
#pragma unroll
    for (int m = 0; m < 8; ++m)
#pragma unroll
      for (int r = 0; r < 2; ++r)
        acc[r][m] = __builtin_amdgcn_mfma_f32_16x16x32_bf16(afr[m], pfr[r], acc[r][m], 0,0,0);
  }
#pragma unroll
  for (int r = 0; r < 2; ++r) {
    int i = i0 + r*16 + l15;
#pragma unroll
    for (int m = 0; m < 8; ++m) {
      bf16x4 o;
#pragma unroll
      for (int j = 0; j < 4; ++j) o[j] = (bf16)(acc[r][m][j] * r_i[r]);
      *(bf16x4*)(aggb + ((size_t)b*Nn + i)*128 + m*16 + g*4) = o;
    }
  }
}

// -------------------------------------------------- fused pool + readout
__global__ __launch_bounds__(256) void pool_readout(
    const bf16* __restrict__ h, const float* __restrict__ mask,
    const float* __restrict__ W1, const float* __restrict__ b1,
    const float* __restrict__ W2, const float* __restrict__ b2,
    float* __restrict__ out) {
  __shared__ float part[3][128];
  __shared__ float pl[128];
  __shared__ float hid[128];
  int b = blockIdx.x, t = threadIdx.x, g = t >> 6, cp = (t & 63)*2;
  float a0 = 0.f, a1 = 0.f;
  for (int n = g*128; n < g*128+128; ++n) {
    float mv = mask[(size_t)b*Nn + n];
    bf16x2 v = *(const bf16x2*)(h + ((size_t)b*Nn + n)*128 + cp);
    a0 = fmaf((float)v[0], mv, a0);
    a1 = fmaf((float)v[1], mv, a1);
  }
  if (g > 0) { part[g-1][cp] = a0; part[g-1][cp+1] = a1; }
  __syncthreads();
  if (g == 0) {
    pl[cp]   = a0 + part[0][cp]   + part[1][cp]   + part[2][cp];
    pl[cp+1] = a1 + part[0][cp+1] + part[1][cp+1] + part[2][cp+1];
  }
  __syncthreads();
  if (t < 128) {
    float a = b1[t];
#pragma unroll 4
    for (int j = 0; j < 128; ++j) a = fmaf(pl[j], W1[j*128 + t], a);
    hid[t] = fmaxf(a, 0.f);
  }
  __syncthreads();
  if (t < 128) {
    float a = b2[t];
#pragma unroll 4
    for (int j = 0; j < 128; ++j) a = fmaf(hid[j], W2[j*128 + t], a);
    out[(size_t)b*128 + t] = a;
  }
}

// -------------------------------------------------- launch
extern "C" void kernel_launch(void* const* d_in, const int* in_sizes, int n_in,
                              void* d_out, int out_size, void* d_ws, size_t ws_size,
                              hipStream_t stream) {
  const float* jets = (const float*)d_in[0];
  const float* mask = (const float*)d_in[1];
  const float* eW0  = (const float*)d_in[2];
  const float* eb0  = (const float*)d_in[3];
  const float* eW1  = (const float*)d_in[4];
  const float* eb1  = (const float*)d_in[5];
  const float* Wm   = (const float*)d_in[6];
  const float* bm   = (const float*)d_in[7];
  const float* Wu   = (const float*)d_in[8];
  const float* bu   = (const float*)d_in[9];
  const float* rW1  = (const float*)d_in[10];
  const float* rb1  = (const float*)d_in[11];
  const float* rW2  = (const float*)d_in[12];
  const float* rb2  = (const float*)d_in[13];
  float* out = (float*)d_out;

  bf16* h    = (bf16*)d_ws;                    // ROWS*128
  bf16* msgT = h    + (size_t)ROWS*128;        // ROWS*128 (layout [b][c][n])
  bf16* aggb = msgT + (size_t)ROWS*128;        // ROWS*128
  bf16* WTe  = aggb + (size_t)ROWS*128;        // 128*128
  bf16* WTm  = WTe  + 128*128;                 // 3*128*128
  bf16* WTu  = WTm  + 3*128*128;               // 3*256*128
  float* marr   = (float*)(WTu + 3*256*128);   // ROWS
  float* larr   = marr + ROWS;                 // ROWS

  prep_all<<<640, 256, 0, stream>>>(eW1, Wm, Wu, WTe, WTm, WTu);
  embed_fused<<<ROWS/128, 256, 0, stream>>>(jets, eW0, eb0, WTe, eb1, h);
  adjstats_kernel<<<Bb*(Nn/32), 256, 0, stream>>>(jets, mask, marr, larr);

  // iter 0
  mfma_dense<128,false,true><<<ROWS/128, 256, 0, stream>>>(h, nullptr, WTm, bm, nullptr, msgT);
  agg_mfma<<<Bb*4, 256, 0, stream>>>(jets, mask, marr, larr, msgT, aggb);
  fused_upd_msg<<<ROWS/256, 512, 0, stream>>>(h, aggb, WTu, bu,
                                              WTm + (size_t)1*128*128, bm + 1*128,
                                              mask, h, msgT);
  // iter 1
  agg_mfma<<<Bb*4, 256, 0, stream>>>(jets, mask, marr, larr, msgT, aggb);
  fused_upd_msg<<<ROWS/256, 512, 0, stream>>>(h, aggb, WTu + (size_t)1*256*128, bu + 1*128,
                                              WTm + (size_t)2*128*128, bm + 2*128,
                                              mask, h, msgT);
  // iter 2
  agg_mfma<<<Bb*4, 256, 0, stream>>>(jets, mask, marr, larr, msgT, aggb);
  mfma_dense<256,true,false><<<ROWS/128, 256, 0, stream>>>(h, aggb, WTu + (size_t)2*256*128, bu + 2*128, mask, h);

  pool_readout<<<Bb, 256, 0, stream>>>(h, mask, rW1, rb1, rW2, rb2, out);
}

// Round 5
// 225.021 us; speedup vs baseline: 9.8324x; 1.1136x over previous
//
#include <hip/hip_runtime.h>
#include <stdint.h>
#include <stddef.h>

#define Bb 128
#define Nn 512
#define Hh 128
#define ROWS (Bb*Nn)

typedef __bf16 bf16;
typedef __bf16 bf16x2 __attribute__((ext_vector_type(2)));
typedef __bf16 bf16x4 __attribute__((ext_vector_type(4)));
typedef __bf16 bf16x8 __attribute__((ext_vector_type(8)));
typedef float  f32x4  __attribute__((ext_vector_type(4)));

__device__ __forceinline__ void glds16(const void* g, void* l) {
  __builtin_amdgcn_global_load_lds(
      (const __attribute__((address_space(1))) void*)g,
      (__attribute__((address_space(3))) void*)l, 16, 0, 0);
}

// -------------------------------------------------- weight prep (all in one)
// fp32 W[k][c] -> bf16 W^T[c][k ^ ((c&7)<<3)]  (swizzle pre-applied)
__global__ __launch_bounds__(256) void prep_all(
    const float* __restrict__ eW1, const float* __restrict__ Wm,
    const float* __restrict__ Wu, bf16* __restrict__ WTe,
    bf16* __restrict__ WTm, bf16* __restrict__ WTu) {
  int idx = blockIdx.x*256 + threadIdx.x;
  if (idx < 16384) {                       // eW1: 128x128
    int k = idx >> 7, c = idx & 127;
    WTe[c*128 + (k ^ ((c & 7) << 3))] = (bf16)eW1[idx];
  } else if (idx < 16384 + 49152) {        // Wm: 3x128x128
    int sub = idx - 16384;
    int m = sub >> 14, r = sub & 16383;
    int k = r >> 7, c = r & 127;
    WTm[m*16384 + c*128 + (k ^ ((c & 7) << 3))] = (bf16)Wm[sub];
  } else if (idx < 16384 + 49152 + 98304) { // Wu: 3x256x128
    int sub = idx - 65536;
    int m = sub >> 15, r = sub & 32767;
    int k = r >> 7, c = r & 127;
    WTu[m*32768 + c*256 + (k ^ ((c & 7) << 3))] = (bf16)Wu[sub];
  }
}

// -------------------------------------------------- fused embed L1+L2+msg0
// h = relu(relu(jets@W0+b0)@W1+b1); msgT0 = relu(h@Wm0+bm0)^T. 128 rows/block.
__global__ __launch_bounds__(256) void embed_msg0(
    const float* __restrict__ jets, const float* __restrict__ W0,
    const float* __restrict__ b0, const bf16* __restrict__ WTe,
    const float* __restrict__ b1, const bf16* __restrict__ WTm0,
    const float* __restrict__ bm0, bf16* __restrict__ h,
    bf16* __restrict__ msgT) {
  __shared__ float sW0[8*128];
  __shared__ float sb0[128];
  __shared__ bf16 h0s[128*128];   // swizzled; reused for h-tile later
  __shared__ bf16 sWT[128*128];   // swizzled W1^T
  const int t = threadIdx.x;
  const int w = t >> 6, lane = t & 63, l15 = lane & 15, g = lane >> 4;
  const int row_blk = blockIdx.x*128;
  for (int q = w; q < 32; q += 4)
    glds16((const char*)WTe + q*1024 + lane*16, (char*)(void*)sWT + q*1024);
  for (int i = t; i < 8*128; i += 256) sW0[i] = W0[i];
  if (t < 128) sb0[t] = b0[t];
  __syncthreads();
  // layer 1: thread owns 1 row, 64 cols
  {
    const int row = t & 127, colbase = (t >> 7) * 64;
    const float4* jp = (const float4*)(jets + ((size_t)row_blk + row)*8);
    float4 x0 = jp[0], x1 = jp[1];
    float x[8] = {x0.x,x0.y,x0.z,x0.w,x1.x,x1.y,x1.z,x1.w};
    const int sw = (row & 7) << 3;
#pragma unroll
    for (int cg = 0; cg < 16; ++cg) {
      int c0 = colbase + cg*4;
      bf16x4 o;
#pragma unroll
      for (int j = 0; j < 4; ++j) {
        float a = sb0[c0+j];
#pragma unroll
        for (int f = 0; f < 8; ++f) a = fmaf(x[f], sW0[f*128 + c0 + j], a);
        o[j] = (bf16)fmaxf(a, 0.f);
      }
      *(bf16x4*)(h0s + row*128 + (c0 ^ sw)) = o;
    }
  }
  __syncthreads();
  // layer 2: MFMA, 4 waves 2x2
  const int wr = (w & 1)*64, wc = (w >> 1)*64;
  f32x4 acc[4][4];
#pragma unroll
  for (int m = 0; m < 4; ++m)
#pragma unroll
    for (int n = 0; n < 4; ++n) acc[m][n] = (f32x4){0.f,0.f,0.f,0.f};
#pragma unroll
  for (int kk = 0; kk < 128; kk += 32) {
    bf16x8 bfr[4], wfr[4];
#pragma unroll
    for (int n = 0; n < 4; ++n) {
      int row = wr + n*16 + l15;
      bfr[n] = *(const bf16x8*)(h0s + row*128 + ((kk + 8*g) ^ ((row & 7) << 3)));
    }
#pragma unroll
    for (int m = 0; m < 4; ++m) {
      int c = wc + m*16 + l15;
      wfr[m] = *(const bf16x8*)(sWT + c*128 + ((kk + 8*g) ^ ((c & 7) << 3)));
    }
#pragma unroll
    for (int m = 0; m < 4; ++m)
#pragma unroll
      for (int n = 0; n < 4; ++n)
        acc[m][n] = __builtin_amdgcn_mfma_f32_16x16x32_bf16(wfr[m], bfr[n], acc[m][n], 0,0,0);
  }
  __syncthreads();   // everyone done reading h0s before overwrite
#pragma unroll
  for (int m = 0; m < 4; ++m) {
    f32x4 bs = *(const f32x4*)(b1 + wc + m*16 + g*4);
#pragma unroll
    for (int n = 0; n < 4; ++n) {
      int lr = wr + n*16 + l15;
      int r = row_blk + lr;
      int c0 = wc + m*16 + g*4;
      bf16x4 o;
#pragma unroll
      for (int j = 0; j < 4; ++j) o[j] = (bf16)fmaxf(acc[m][n][j] + bs[j], 0.f);
      *(bf16x4*)(h + (size_t)r*128 + c0) = o;
      *(bf16x4*)(h0s + lr*128 + (c0 ^ ((lr & 7) << 3))) = o;
    }
  }
  __syncthreads();
  // msg0: msgT = relu(htile @ Wm0 + bm0), TRANSOUT; Wm0 frags from global(L2)
  {
    f32x4 acc2[4][4];
#pragma unroll
    for (int m = 0; m < 4; ++m)
#pragma unroll
      for (int n = 0; n < 4; ++n) acc2[m][n] = (f32x4){0.f,0.f,0.f,0.f};
#pragma unroll
    for (int kk = 0; kk < 128; kk += 32) {
      bf16x8 bfr[4], wfr[4];
#pragma unroll
      for (int n = 0; n < 4; ++n) {
        int lr = wr + n*16 + l15;
        bfr[n] = *(const bf16x8*)(h0s + lr*128 + ((kk + 8*g) ^ ((lr & 7) << 3)));
      }
#pragma unroll
      for (int m = 0; m < 4; ++m) {
        int c = wc + m*16 + l15;
        wfr[m] = *(const bf16x8*)(WTm0 + c*128 + ((kk + 8*g) ^ ((c & 7) << 3)));
      }
#pragma unroll
      for (int m = 0; m < 4; ++m)
#pragma unroll
        for (int n = 0; n < 4; ++n)
          acc2[m][n] = __builtin_amdgcn_mfma_f32_16x16x32_bf16(bfr[n], wfr[m], acc2[m][n], 0,0,0);
    }
    const int b = row_blk >> 9;
    const int rbase = (row_blk & 511) + wr;
#pragma unroll
    for (int m = 0; m < 4; ++m) {
      int c = wc + m*16 + l15;
      float bc = bm0[c];
#pragma unroll
      for (int n = 0; n < 4; ++n) {
        int rl = rbase + n*16 + g*4;
        bf16x4 o;
#pragma unroll
        for (int j = 0; j < 4; ++j) o[j] = (bf16)fmaxf(acc2[m][n][j] + bc, 0.f);
        *(bf16x4*)(msgT + ((size_t)(b*128 + c))*512 + rl) = o;
      }
    }
  }
}

// -------------------------------------------------- MFMA dense (last update)
template<int K, bool MASKMUL, bool TRANSOUT>
__global__ __launch_bounds__(256) void mfma_dense(
    const bf16* __restrict__ A0, const bf16* __restrict__ A1,
    const bf16* __restrict__ WT, const float* __restrict__ bias,
    const float* __restrict__ mask, bf16* __restrict__ out) {
  __shared__ bf16 sWT[128*K];
  const int t = threadIdx.x;
  const int w = t >> 6, lane = t & 63;
  const int l15 = lane & 15, g = lane >> 4;
  const int CH = (128*K*2)/1024;
  for (int q = w; q < CH; q += 4)
    glds16((const char*)WT + q*1024 + lane*16, (char*)(void*)sWT + q*1024);

  const int row_blk = blockIdx.x*128;
  const int wr = (w & 1)*64, wc = (w >> 1)*64;
  int rowg[4];
#pragma unroll
  for (int n = 0; n < 4; ++n) rowg[n] = row_blk + wr + n*16 + l15;
  f32x4 acc[4][4];
#pragma unroll
  for (int m = 0; m < 4; ++m)
#pragma unroll
    for (int n = 0; n < 4; ++n) acc[m][n] = (f32x4){0.f,0.f,0.f,0.f};
  __syncthreads();

#pragma unroll
  for (int kk = 0; kk < K; kk += 32) {
    const bf16* base; int kl;
    if (K == 128) { base = A0; kl = kk; }
    else          { base = (kk < 128) ? A0 : A1; kl = kk & 127; }
    bf16x8 bfr[4];
#pragma unroll
    for (int n = 0; n < 4; ++n)
      bfr[n] = *(const bf16x8*)(base + (size_t)rowg[n]*128 + kl + 8*g);
    bf16x8 wfr[4];
#pragma unroll
    for (int m = 0; m < 4; ++m) {
      int c = wc + m*16 + l15;
      int kidx = (kk + 8*g) ^ ((c & 7) << 3);
      wfr[m] = *(const bf16x8*)(sWT + c*K + kidx);
    }
#pragma unroll
    for (int m = 0; m < 4; ++m)
#pragma unroll
      for (int n = 0; n < 4; ++n) {
        if (TRANSOUT)
          acc[m][n] = __builtin_amdgcn_mfma_f32_16x16x32_bf16(bfr[n], wfr[m], acc[m][n], 0,0,0);
        else
          acc[m][n] = __builtin_amdgcn_mfma_f32_16x16x32_bf16(wfr[m], bfr[n], acc[m][n], 0,0,0);
      }
  }

  if (!TRANSOUT) {
#pragma unroll
    for (int m = 0; m < 4; ++m) {
      f32x4 bs = *(const f32x4*)(bias + wc + m*16 + g*4);
#pragma unroll
      for (int n = 0; n < 4; ++n) {
        int r = rowg[n];
        float mv = MASKMUL ? mask[r] : 1.f;
        f32x4 v = acc[m][n];
        bf16x4 o;
#pragma unroll
        for (int j = 0; j < 4; ++j) {
          float x = fmaxf(v[j] + bs[j], 0.f);
          if (MASKMUL) x *= mv;
          o[j] = (bf16)x;
        }
        *(bf16x4*)(out + (size_t)r*128 + wc + m*16 + g*4) = o;
      }
    }
  } else {
    const int b = row_blk >> 9;
    const int rbase = (row_blk & 511) + wr;
#pragma unroll
    for (int m = 0; m < 4; ++m) {
      int c = wc + m*16 + l15;
      float bc = bias[c];
#pragma unroll
      for (int n = 0; n < 4; ++n) {
        int rl = rbase + n*16 + g*4;
        f32x4 v = acc[m][n];
        bf16x4 o;
#pragma unroll
        for (int j = 0; j < 4; ++j) o[j] = (bf16)fmaxf(v[j] + bc, 0.f);
        *(bf16x4*)(out + ((size_t)(b*128 + c))*512 + rl) = o;
      }
    }
  }
}

// -------------------------------------------------- fused update + msg
__global__ __launch_bounds__(512) void fused_upd_msg(
    const bf16* __restrict__ h, const bf16* __restrict__ aggb,
    const bf16* __restrict__ WTu, const float* __restrict__ bu,
    const bf16* __restrict__ WTm, const float* __restrict__ bm,
    const float* __restrict__ mask, bf16* __restrict__ hout,
    bf16* __restrict__ msgT) {
  __shared__ bf16 sWTu[128*256];
  __shared__ bf16 htile[256*128];  // swizzled
  const int t = threadIdx.x;
  const int w = t >> 6, lane = t & 63, l15 = lane & 15, g = lane >> 4;
  for (int q = w; q < 64; q += 8)
    glds16((const char*)WTu + q*1024 + lane*16, (char*)(void*)sWTu + q*1024);

  const int row_blk = blockIdx.x*256;
  // ---- GEMM1: 8 waves = 4 row-groups x 2 col-groups
  {
    const int wr = (w & 3)*64, wc = (w >> 2)*64;
    int rowg[4];
#pragma unroll
    for (int n = 0; n < 4; ++n) rowg[n] = row_blk + wr + n*16 + l15;
    f32x4 acc[4][4];
#pragma unroll
    for (int m = 0; m < 4; ++m)
#pragma unroll
      for (int n = 0; n < 4; ++n) acc[m][n] = (f32x4){0.f,0.f,0.f,0.f};
    __syncthreads();
#pragma unroll
    for (int kk = 0; kk < 256; kk += 32) {
      const bf16* base = (kk < 128) ? h : aggb;
      int kl = kk & 127;
      bf16x8 bfr[4];
#pragma unroll
      for (int n = 0; n < 4; ++n)
        bfr[n] = *(const bf16x8*)(base + (size_t)rowg[n]*128 + kl + 8*g);
      bf16x8 wfr[4];
#pragma unroll
      for (int m = 0; m < 4; ++m) {
        int c = wc + m*16 + l15;
        wfr[m] = *(const bf16x8*)(sWTu + c*256 + ((kk + 8*g) ^ ((c & 7) << 3)));
      }
#pragma unroll
      for (int m = 0; m < 4; ++m)
#pragma unroll
        for (int n = 0; n < 4; ++n)
          acc[m][n] = __builtin_amdgcn_mfma_f32_16x16x32_bf16(wfr[m], bfr[n], acc[m][n], 0,0,0);
    }
#pragma unroll
    for (int m = 0; m < 4; ++m) {
      f32x4 bs = *(const f32x4*)(bu + wc + m*16 + g*4);
#pragma unroll
      for (int n = 0; n < 4; ++n) {
        int r = rowg[n];
        int lr = wr + n*16 + l15;
        float mv = mask[r];
        bf16x4 o;
#pragma unroll
        for (int j = 0; j < 4; ++j)
          o[j] = (bf16)(fmaxf(acc[m][n][j] + bs[j], 0.f) * mv);
        int c0 = wc + m*16 + g*4;
        *(bf16x4*)(hout + (size_t)r*128 + c0) = o;
        *(bf16x4*)(htile + lr*128 + (c0 ^ ((lr & 7) << 3))) = o;
      }
    }
  }
  __syncthreads();
  // ---- GEMM2: msgT = relu(htile @ Wm + bm), TRANSOUT
  {
    const int wr = (w & 3)*64, wc = (w >> 2)*64;
    f32x4 acc[4][4];
#pragma unroll
    for (int m = 0; m < 4; ++m)
#pragma unroll
      for (int n = 0; n < 4; ++n) acc[m][n] = (f32x4){0.f,0.f,0.f,0.f};
#pragma unroll
    for (int kk = 0; kk < 128; kk += 32) {
      bf16x8 bfr[4], wfr[4];
#pragma unroll
      for (int n = 0; n < 4; ++n) {
        int lr = wr + n*16 + l15;
        bfr[n] = *(const bf16x8*)(htile + lr*128 + ((kk + 8*g) ^ ((lr & 7) << 3)));
      }
#pragma unroll
      for (int m = 0; m < 4; ++m) {
        int c = wc + m*16 + l15;
        wfr[m] = *(const bf16x8*)(WTm + c*128 + ((kk + 8*g) ^ ((c & 7) << 3)));
      }
#pragma unroll
      for (int m = 0; m < 4; ++m)
#pragma unroll
        for (int n = 0; n < 4; ++n)
          acc[m][n] = __builtin_amdgcn_mfma_f32_16x16x32_bf16(bfr[n], wfr[m], acc[m][n], 0,0,0);
    }
    const int b = row_blk >> 9;
    const int rbase = (row_blk & 511) + wr;
#pragma unroll
    for (int m = 0; m < 4; ++m) {
      int c = wc + m*16 + l15;
      float bc = bm[c];
#pragma unroll
      for (int n = 0; n < 4; ++n) {
        int rl = rbase + n*16 + g*4;
        bf16x4 o;
#pragma unroll
        for (int j = 0; j < 4; ++j) o[j] = (bf16)fmaxf(acc[m][n][j] + bc, 0.f);
        *(bf16x4*)(msgT + ((size_t)(b*128 + c))*512 + rl) = o;
      }
    }
  }
}

// -------------------------------------------------- agg = P @ msg  (MFMA)
// E = exp(2xi.xj - |xj|^2 - pen_j - |xi|^2) = exp(-d2 - pen) in (0,1].
// COMPUTE_L: also computes l_i = sum_j E (f32) and stores rsum = 1/l_i.
// XCD-aware: b = wgid & 127 keeps a batch's blocks on one XCD.
template<bool COMPUTE_L>
__global__ __launch_bounds__(256) void agg_mfma(
    const float* __restrict__ jets, const float* __restrict__ mask,
    float* __restrict__ rsum, const bf16* __restrict__ msgT,
    bf16* __restrict__ aggb) {
  __shared__ float Xs[Nn*9];
  __shared__ float cbs[Nn];
  int t = threadIdx.x;
  int b  = blockIdx.x & 127;
  int ic = blockIdx.x >> 7;
  const float* jb = jets + (size_t)b*Nn*8;
  for (int j = t; j < Nn; j += 256) {
    float s2 = 0.f;
#pragma unroll
    for (int f = 0; f < 8; ++f) { float v = jb[j*8+f]; Xs[j*9+f] = v; s2 = fmaf(v,v,s2); }
    cbs[j] = s2 + (mask[(size_t)b*Nn+j] > 0.f ? 0.f : 1e9f);
  }
  __syncthreads();
  int w = t >> 6, lane = t & 63, l15 = lane & 15, g = lane >> 4;
  int i0 = ic*128 + w*32;
  float xi2[2][8];
  float sqi[2], r_i[2], lsum[2];
#pragma unroll
  for (int r = 0; r < 2; ++r) {
    int i = i0 + r*16 + l15;
    float sq = 0.f;
#pragma unroll
    for (int f = 0; f < 8; ++f) {
      float v = Xs[i*9+f];
      xi2[r][f] = 2.f*v;
      sq = fmaf(v, v, sq);
    }
    sqi[r] = sq;
    lsum[r] = 0.f;
    if (!COMPUTE_L) r_i[r] = rsum[(size_t)b*Nn+i];
  }
  f32x4 acc[2][8];
#pragma unroll
  for (int r = 0; r < 2; ++r)
#pragma unroll
    for (int m = 0; m < 8; ++m) acc[r][m] = (f32x4){0.f,0.f,0.f,0.f};
  const bf16* mB = msgT + (size_t)b*128*512;
#pragma unroll 2
  for (int j0 = 0; j0 < Nn; j0 += 32) {
    bf16x8 afr[8];
#pragma unroll
    for (int m = 0; m < 8; ++m)
      afr[m] = *(const bf16x8*)(mB + (size_t)(m*16 + l15)*512 + j0 + 8*g);
    bf16x8 pfr[2];
#pragma unroll
    for (int r = 0; r < 2; ++r)
#pragma unroll
      for (int e = 0; e < 8; ++e) {
        int j = j0 + 8*g + e;
        float d = -(cbs[j] + sqi[r]);
#pragma unroll
        for (int f = 0; f < 8; ++f) d = fmaf(xi2[r][f], Xs[j*9+f], d);
        float ev = __expf(d);
        if (COMPUTE_L) lsum[r] += ev;
        pfr[r][e] = (bf16)ev;
      }
#pragma unroll
    for (int m = 0; m < 8; ++m)
#pragma unroll
      for (int r = 0; r < 2; ++r)
        acc[r][m] = __builtin_amdgcn_mfma_f32_16x16x32_bf16(afr[m], pfr[r], acc[r][m], 0,0,0);
  }
  if (COMPUTE_L) {
#pragma unroll
    for (int r = 0; r < 2; ++r) {
      float s = lsum[r];
      s += __shfl_xor(s, 16, 64);
      s += __shfl_xor(s, 32, 64);
      r_i[r] = 1.f/s;
      if (g == 0) rsum[(size_t)b*Nn + i0 + r*16 + l15] = r_i[r];
    }
  }
#pragma unroll
  for (int r = 0; r < 2; ++r) {
    int i = i0 + r*16 + l15;
#pragma unroll
    for (int m = 0; m < 8; ++m) {
      bf16x4 o;
#pragma unroll
      for (int j = 0; j < 4; ++j) o[j] = (bf16)(acc[r][m][j] * r_i[r]);
      *(bf16x4*)(aggb + ((size_t)b*Nn + i)*128 + m*16 + g*4) = o;
    }
  }
}

// -------------------------------------------------- fused pool + readout
__global__ __launch_bounds__(256) void pool_readout(
    const bf16* __restrict__ h, const float* __restrict__ mask,
    const float* __restrict__ W1, const float* __restrict__ b1,
    const float* __restrict__ W2, const float* __restrict__ b2,
    float* __restrict__ out) {
  __shared__ float part[3][128];
  __shared__ float pl[128];
  __shared__ float hid[128];
  int b = blockIdx.x, t = threadIdx.x, g = t >> 6, cp = (t & 63)*2;
  float a0 = 0.f, a1 = 0.f;
  for (int n = g*128; n < g*128+128; ++n) {
    float mv = mask[(size_t)b*Nn + n];
    bf16x2 v = *(const bf16x2*)(h + ((size_t)b*Nn + n)*128 + cp);
    a0 = fmaf((float)v[0], mv, a0);
    a1 = fmaf((float)v[1], mv, a1);
  }
  if (g > 0) { part[g-1][cp] = a0; part[g-1][cp+1] = a1; }
  __syncthreads();
  if (g == 0) {
    pl[cp]   = a0 + part[0][cp]   + part[1][cp]   + part[2][cp];
    pl[cp+1] = a1 + part[0][cp+1] + part[1][cp+1] + part[2][cp+1];
  }
  __syncthreads();
  if (t < 128) {
    float a = b1[t];
#pragma unroll 4
    for (int j = 0; j < 128; ++j) a = fmaf(pl[j], W1[j*128 + t], a);
    hid[t] = fmaxf(a, 0.f);
  }
  __syncthreads();
  if (t < 128) {
    float a = b2[t];
#pragma unroll 4
    for (int j = 0; j < 128; ++j) a = fmaf(hid[j], W2[j*128 + t], a);
    out[(size_t)b*128 + t] = a;
  }
}

// -------------------------------------------------- launch
extern "C" void kernel_launch(void* const* d_in, const int* in_sizes, int n_in,
                              void* d_out, int out_size, void* d_ws, size_t ws_size,
                              hipStream_t stream) {
  const float* jets = (const float*)d_in[0];
  const float* mask = (const float*)d_in[1];
  const float* eW0  = (const float*)d_in[2];
  const float* eb0  = (const float*)d_in[3];
  const float* eW1  = (const float*)d_in[4];
  const float* eb1  = (const float*)d_in[5];
  const float* Wm   = (const float*)d_in[6];
  const float* bm   = (const float*)d_in[7];
  const float* Wu   = (const float*)d_in[8];
  const float* bu   = (const float*)d_in[9];
  const float* rW1  = (const float*)d_in[10];
  const float* rb1  = (const float*)d_in[11];
  const float* rW2  = (const float*)d_in[12];
  const float* rb2  = (const float*)d_in[13];
  float* out = (float*)d_out;

  bf16* h    = (bf16*)d_ws;                    // ROWS*128
  bf16* msgT = h    + (size_t)ROWS*128;        // ROWS*128 (layout [b][c][n])
  bf16* aggb = msgT + (size_t)ROWS*128;        // ROWS*128
  bf16* WTe  = aggb + (size_t)ROWS*128;        // 128*128
  bf16* WTm  = WTe  + 128*128;                 // 3*128*128
  bf16* WTu  = WTm  + 3*128*128;               // 3*256*128
  float* rsum = (float*)(WTu + 3*256*128);     // ROWS (1/l_i)

  prep_all<<<640, 256, 0, stream>>>(eW1, Wm, Wu, WTe, WTm, WTu);
  embed_msg0<<<ROWS/128, 256, 0, stream>>>(jets, eW0, eb0, WTe, eb1,
                                           WTm, bm, h, msgT);
  // iter 0 (computes 1/l_i on the fly)
  agg_mfma<true><<<Bb*4, 256, 0, stream>>>(jets, mask, rsum, msgT, aggb);
  fused_upd_msg<<<ROWS/256, 512, 0, stream>>>(h, aggb, WTu, bu,
                                              WTm + (size_t)1*128*128, bm + 1*128,
                                              mask, h, msgT);
  // iter 1
  agg_mfma<false><<<Bb*4, 256, 0, stream>>>(jets, mask, rsum, msgT, aggb);
  fused_upd_msg<<<ROWS/256, 512, 0, stream>>>(h, aggb, WTu + (size_t)1*256*128, bu + 1*128,
                                              WTm + (size_t)2*128*128, bm + 2*128,
                                              mask, h, msgT);
  // iter 2
  agg_mfma<false><<<Bb*4, 256, 0, stream>>>(jets, mask, rsum, msgT, aggb);
  mfma_dense<256,true,false><<<ROWS/128, 256, 0, stream>>>(h, aggb, WTu + (size_t)2*256*128, bu + 2*128, mask, h);

  pool_readout<<<Bb, 256, 0, stream>>>(h, mask, rW1, rb1, rW2, rb2, out);
}

// Round 7
// 212.735 us; speedup vs baseline: 10.4002x; 1.0578x over previous
//
#include <hip/hip_runtime.h>
#include <stdint.h>
#include <stddef.h>

#define Bb 128
#define Nn 512
#define Hh 128
#define ROWS (Bb*Nn)

typedef __bf16 bf16;
typedef __bf16 bf16x2 __attribute__((ext_vector_type(2)));
typedef __bf16 bf16x4 __attribute__((ext_vector_type(4)));
typedef __bf16 bf16x8 __attribute__((ext_vector_type(8)));
typedef float  f32x4  __attribute__((ext_vector_type(4)));

__device__ __forceinline__ void glds16(const void* g, void* l) {
  __builtin_amdgcn_global_load_lds(
      (const __attribute__((address_space(1))) void*)g,
      (__attribute__((address_space(3))) void*)l, 16, 0, 0);
}

// -------------------------------------------------- weight prep (all in one)
// fp32 W[k][c] -> bf16 W^T[c][k ^ ((c&7)<<3)]  (swizzle pre-applied)
__global__ __launch_bounds__(256) void prep_all(
    const float* __restrict__ eW1, const float* __restrict__ Wm,
    const float* __restrict__ Wu, bf16* __restrict__ WTe,
    bf16* __restrict__ WTm, bf16* __restrict__ WTu) {
  int idx = blockIdx.x*256 + threadIdx.x;
  if (idx < 16384) {                       // eW1: 128x128
    int k = idx >> 7, c = idx & 127;
    WTe[c*128 + (k ^ ((c & 7) << 3))] = (bf16)eW1[idx];
  } else if (idx < 16384 + 49152) {        // Wm: 3x128x128
    int sub = idx - 16384;
    int m = sub >> 14, r = sub & 16383;
    int k = r >> 7, c = r & 127;
    WTm[m*16384 + c*128 + (k ^ ((c & 7) << 3))] = (bf16)Wm[sub];
  } else if (idx < 16384 + 49152 + 98304) { // Wu: 3x256x128
    int sub = idx - 65536;
    int m = sub >> 15, r = sub & 32767;
    int k = r >> 7, c = r & 127;
    WTu[m*32768 + c*256 + (k ^ ((c & 7) << 3))] = (bf16)Wu[sub];
  }
}

// -------------------------------------------------- fused embed L1+L2+msg0
// h = relu(relu(jets@W0+b0)@W1+b1); msgT0 = relu(h@Wm0+bm0)^T. 128 rows/block.
__global__ __launch_bounds__(256) void embed_msg0(
    const float* __restrict__ jets, const float* __restrict__ W0,
    const float* __restrict__ b0, const bf16* __restrict__ WTe,
    const float* __restrict__ b1, const bf16* __restrict__ WTm0,
    const float* __restrict__ bm0, bf16* __restrict__ h,
    bf16* __restrict__ msgT) {
  __shared__ float sW0[8*128];
  __shared__ float sb0[128];
  __shared__ bf16 h0s[128*128];   // swizzled; reused for h-tile later
  __shared__ bf16 sWT[128*128];   // swizzled W1^T
  const int t = threadIdx.x;
  const int w = t >> 6, lane = t & 63, l15 = lane & 15, g = lane >> 4;
  const int row_blk = blockIdx.x*128;
  for (int q = w; q < 32; q += 4)
    glds16((const char*)WTe + q*1024 + lane*16, (char*)(void*)sWT + q*1024);
  for (int i = t; i < 8*128; i += 256) sW0[i] = W0[i];
  if (t < 128) sb0[t] = b0[t];
  __syncthreads();
  // layer 1: thread owns 1 row, 64 cols
  {
    const int row = t & 127, colbase = (t >> 7) * 64;
    const float4* jp = (const float4*)(jets + ((size_t)row_blk + row)*8);
    float4 x0 = jp[0], x1 = jp[1];
    float x[8] = {x0.x,x0.y,x0.z,x0.w,x1.x,x1.y,x1.z,x1.w};
    const int sw = (row & 7) << 3;
#pragma unroll
    for (int cg = 0; cg < 16; ++cg) {
      int c0 = colbase + cg*4;
      bf16x4 o;
#pragma unroll
      for (int j = 0; j < 4; ++j) {
        float a = sb0[c0+j];
#pragma unroll
        for (int f = 0; f < 8; ++f) a = fmaf(x[f], sW0[f*128 + c0 + j], a);
        o[j] = (bf16)fmaxf(a, 0.f);
      }
      *(bf16x4*)(h0s + row*128 + (c0 ^ sw)) = o;
    }
  }
  __syncthreads();
  // layer 2: MFMA, 4 waves 2x2
  const int wr = (w & 1)*64, wc = (w >> 1)*64;
  f32x4 acc[4][4];
#pragma unroll
  for (int m = 0; m < 4; ++m)
#pragma unroll
    for (int n = 0; n < 4; ++n) acc[m][n] = (f32x4){0.f,0.f,0.f,0.f};
#pragma unroll
  for (int kk = 0; kk < 128; kk += 32) {
    bf16x8 bfr[4], wfr[4];
#pragma unroll
    for (int n = 0; n < 4; ++n) {
      int row = wr + n*16 + l15;
      bfr[n] = *(const bf16x8*)(h0s + row*128 + ((kk + 8*g) ^ ((row & 7) << 3)));
    }
#pragma unroll
    for (int m = 0; m < 4; ++m) {
      int c = wc + m*16 + l15;
      wfr[m] = *(const bf16x8*)(sWT + c*128 + ((kk + 8*g) ^ ((c & 7) << 3)));
    }
#pragma unroll
    for (int m = 0; m < 4; ++m)
#pragma unroll
      for (int n = 0; n < 4; ++n)
        acc[m][n] = __builtin_amdgcn_mfma_f32_16x16x32_bf16(wfr[m], bfr[n], acc[m][n], 0,0,0);
  }
  __syncthreads();   // everyone done reading h0s before overwrite
#pragma unroll
  for (int m = 0; m < 4; ++m) {
    f32x4 bs = *(const f32x4*)(b1 + wc + m*16 + g*4);
#pragma unroll
    for (int n = 0; n < 4; ++n) {
      int lr = wr + n*16 + l15;
      int r = row_blk + lr;
      int c0 = wc + m*16 + g*4;
      bf16x4 o;
#pragma unroll
      for (int j = 0; j < 4; ++j) o[j] = (bf16)fmaxf(acc[m][n][j] + bs[j], 0.f);
      *(bf16x4*)(h + (size_t)r*128 + c0) = o;
      *(bf16x4*)(h0s + lr*128 + (c0 ^ ((lr & 7) << 3))) = o;
    }
  }
  __syncthreads();
  // msg0: msgT = relu(htile @ Wm0 + bm0), TRANSOUT; Wm0 frags from global(L2)
  {
    f32x4 acc2[4][4];
#pragma unroll
    for (int m = 0; m < 4; ++m)
#pragma unroll
      for (int n = 0; n < 4; ++n) acc2[m][n] = (f32x4){0.f,0.f,0.f,0.f};
#pragma unroll
    for (int kk = 0; kk < 128; kk += 32) {
      bf16x8 bfr[4], wfr[4];
#pragma unroll
      for (int n = 0; n < 4; ++n) {
        int lr = wr + n*16 + l15;
        bfr[n] = *(const bf16x8*)(h0s + lr*128 + ((kk + 8*g) ^ ((lr & 7) << 3)));
      }
#pragma unroll
      for (int m = 0; m < 4; ++m) {
        int c = wc + m*16 + l15;
        wfr[m] = *(const bf16x8*)(WTm0 + c*128 + ((kk + 8*g) ^ ((c & 7) << 3)));
      }
#pragma unroll
      for (int m = 0; m < 4; ++m)
#pragma unroll
        for (int n = 0; n < 4; ++n)
          acc2[m][n] = __builtin_amdgcn_mfma_f32_16x16x32_bf16(bfr[n], wfr[m], acc2[m][n], 0,0,0);
    }
    const int b = row_blk >> 9;
    const int rbase = (row_blk & 511) + wr;
#pragma unroll
    for (int m = 0; m < 4; ++m) {
      int c = wc + m*16 + l15;
      float bc = bm0[c];
#pragma unroll
      for (int n = 0; n < 4; ++n) {
        int rl = rbase + n*16 + g*4;
        bf16x4 o;
#pragma unroll
        for (int j = 0; j < 4; ++j) o[j] = (bf16)fmaxf(acc2[m][n][j] + bc, 0.f);
        *(bf16x4*)(msgT + ((size_t)(b*128 + c))*512 + rl) = o;
      }
    }
  }
}

// -------------------------------------------------- fused per-iteration kernel
// Phase A: agg = softmax(P) @ msgTin  -> LDS tile (never hits HBM)
// Phase B: h_new = relu([h, agg] @ Wu + bu) * mask  (in-place h, own rows only)
// Phase C (DO_MSG): msgTout = relu(h_new @ Wm + bm)^T
// msgTin != msgTout (ping-pong buffers) -- cross-block WAR race otherwise:
// sibling blocks of batch b still READ msgTin while we'd overwrite it.
// Block = (batch b = wgid&127 [XCD-pinned], 128-row chunk ic = wgid>>7).
template<bool COMPUTE_L, bool DO_MSG>
__global__ __launch_bounds__(256) void iter_fused(
    const float* __restrict__ jets, const float* __restrict__ mask,
    float* __restrict__ rsum, const bf16* __restrict__ msgTin,
    bf16* __restrict__ h,
    const bf16* __restrict__ WTu, const float* __restrict__ bu,
    const bf16* __restrict__ WTm, const float* __restrict__ bm,
    bf16* __restrict__ msgTout) {
  __shared__ __align__(16) char smem[65536];
  float* Xs   = (float*)smem;                 // [512*9]   18KB (phase A)
  float* cbs  = (float*)(smem + 18432);       // [512]      2KB (phase A)
  bf16*  htile = (bf16*)smem;                 // [128][128] 32KB (phase B/C)
  bf16*  aggs  = (bf16*)(smem + 32768);       // [128][128] 32KB
  const int t = threadIdx.x;
  const int b  = blockIdx.x & 127;
  const int ic = blockIdx.x >> 7;             // 0..3
  const int i0 = ic*128;
  const int w = t >> 6, lane = t & 63, l15 = lane & 15, g = lane >> 4;

  // ---- stage Xs / cbs
  const float* jb = jets + (size_t)b*Nn*8;
  for (int j = t; j < Nn; j += 256) {
    float s2 = 0.f;
#pragma unroll
    for (int f = 0; f < 8; ++f) { float v = jb[j*8+f]; Xs[j*9+f] = v; s2 = fmaf(v,v,s2); }
    cbs[j] = s2 + (mask[(size_t)b*Nn+j] > 0.f ? 0.f : 1e9f);
  }
  __syncthreads();

  // ================= Phase A: agg rows i0 + w*32 .. +31
  {
    const int i0w = i0 + w*32;
    float xi2[2][8], sqi[2], r_i[2], lsum[2];
#pragma unroll
    for (int r = 0; r < 2; ++r) {
      int i = i0w + r*16 + l15;
      float sq = 0.f;
#pragma unroll
      for (int f = 0; f < 8; ++f) {
        float v = Xs[i*9+f];
        xi2[r][f] = 2.f*v;
        sq = fmaf(v, v, sq);
      }
      sqi[r] = sq;
      lsum[r] = 0.f;
      if (!COMPUTE_L) r_i[r] = rsum[(size_t)b*Nn+i];
    }
    f32x4 acc[2][8];
#pragma unroll
    for (int r = 0; r < 2; ++r)
#pragma unroll
      for (int m = 0; m < 8; ++m) acc[r][m] = (f32x4){0.f,0.f,0.f,0.f};
    const bf16* mB = msgTin + (size_t)b*128*512;
#pragma unroll 2
    for (int j0 = 0; j0 < Nn; j0 += 32) {
      bf16x8 afr[8];
#pragma unroll
      for (int m = 0; m < 8; ++m)
        afr[m] = *(const bf16x8*)(mB + (size_t)(m*16 + l15)*512 + j0 + 8*g);
      bf16x8 pfr[2];
#pragma unroll
      for (int r = 0; r < 2; ++r)
#pragma unroll
        for (int e = 0; e < 8; ++e) {
          int j = j0 + 8*g + e;
          float d = -(cbs[j] + sqi[r]);
#pragma unroll
          for (int f = 0; f < 8; ++f) d = fmaf(xi2[r][f], Xs[j*9+f], d);
          float ev = __expf(d);
          if (COMPUTE_L) lsum[r] += ev;
          pfr[r][e] = (bf16)ev;
        }
#pragma unroll
      for (int m = 0; m < 8; ++m)
#pragma unroll
        for (int r = 0; r < 2; ++r)
          acc[r][m] = __builtin_amdgcn_mfma_f32_16x16x32_bf16(afr[m], pfr[r], acc[r][m], 0,0,0);
    }
    if (COMPUTE_L) {
#pragma unroll
      for (int r = 0; r < 2; ++r) {
        float s = lsum[r];
        s += __shfl_xor(s, 16, 64);
        s += __shfl_xor(s, 32, 64);
        r_i[r] = 1.f/s;
        if (g == 0) rsum[(size_t)b*Nn + i0w + r*16 + l15] = r_i[r];
      }
    }
    // epilogue -> aggs LDS (swizzled)
#pragma unroll
    for (int r = 0; r < 2; ++r) {
      int lr = w*32 + r*16 + l15;      // local row 0..127
#pragma unroll
      for (int m = 0; m < 8; ++m) {
        bf16x4 o;
#pragma unroll
        for (int j = 0; j < 4; ++j) o[j] = (bf16)(acc[r][m][j] * r_i[r]);
        int c0 = m*16 + g*4;
        *(bf16x4*)(aggs + lr*128 + (c0 ^ ((lr & 7) << 3))) = o;
      }
    }
  }
  __syncthreads();   // aggs visible; Xs dead

  // ================= Phase B: h_new = relu([h|agg] @ Wu + bu) * mask
  const int wr = (w & 1)*64, wc = (w >> 1)*64;
  const size_t growbase = (size_t)b*Nn + i0;
  {
    f32x4 acc[4][4];
#pragma unroll
    for (int m = 0; m < 4; ++m)
#pragma unroll
      for (int n = 0; n < 4; ++n) acc[m][n] = (f32x4){0.f,0.f,0.f,0.f};
#pragma unroll
    for (int kk = 0; kk < 256; kk += 32) {
      bf16x8 bfr[4];
      if (kk < 128) {
#pragma unroll
        for (int n = 0; n < 4; ++n)
          bfr[n] = *(const bf16x8*)(h + (growbase + wr + n*16 + l15)*128 + kk + 8*g);
      } else {
#pragma unroll
        for (int n = 0; n < 4; ++n) {
          int lr = wr + n*16 + l15;
          int kl = (kk - 128) + 8*g;
          bfr[n] = *(const bf16x8*)(aggs + lr*128 + (kl ^ ((lr & 7) << 3)));
        }
      }
      bf16x8 wfr[4];
#pragma unroll
      for (int m = 0; m < 4; ++m) {
        int c = wc + m*16 + l15;
        wfr[m] = *(const bf16x8*)(WTu + c*256 + ((kk + 8*g) ^ ((c & 7) << 3)));
      }
#pragma unroll
      for (int m = 0; m < 4; ++m)
#pragma unroll
        for (int n = 0; n < 4; ++n)
          acc[m][n] = __builtin_amdgcn_mfma_f32_16x16x32_bf16(wfr[m], bfr[n], acc[m][n], 0,0,0);
    }
    __syncthreads();  // all waves' h reads drained before in-place write
#pragma unroll
    for (int m = 0; m < 4; ++m) {
      f32x4 bs = *(const f32x4*)(bu + wc + m*16 + g*4);
#pragma unroll
      for (int n = 0; n < 4; ++n) {
        int lr = wr + n*16 + l15;
        size_t r = growbase + lr;
        float mv = mask[r];
        bf16x4 o;
#pragma unroll
        for (int j = 0; j < 4; ++j)
          o[j] = (bf16)(fmaxf(acc[m][n][j] + bs[j], 0.f) * mv);
        int c0 = wc + m*16 + g*4;
        *(bf16x4*)(h + r*128 + c0) = o;
        if (DO_MSG)
          *(bf16x4*)(htile + lr*128 + (c0 ^ ((lr & 7) << 3))) = o;
      }
    }
  }
  if (!DO_MSG) return;
  __syncthreads();   // htile visible

  // ================= Phase C: msgTout = relu(h_new @ Wm + bm)^T
  {
    f32x4 acc[4][4];
#pragma unroll
    for (int m = 0; m < 4; ++m)
#pragma unroll
      for (int n = 0; n < 4; ++n) acc[m][n] = (f32x4){0.f,0.f,0.f,0.f};
#pragma unroll
    for (int kk = 0; kk < 128; kk += 32) {
      bf16x8 bfr[4], wfr[4];
#pragma unroll
      for (int n = 0; n < 4; ++n) {
        int lr = wr + n*16 + l15;
        bfr[n] = *(const bf16x8*)(htile + lr*128 + ((kk + 8*g) ^ ((lr & 7) << 3)));
      }
#pragma unroll
      for (int m = 0; m < 4; ++m) {
        int c = wc + m*16 + l15;
        wfr[m] = *(const bf16x8*)(WTm + c*128 + ((kk + 8*g) ^ ((c & 7) << 3)));
      }
#pragma unroll
      for (int m = 0; m < 4; ++m)
#pragma unroll
        for (int n = 0; n < 4; ++n)
          acc[m][n] = __builtin_amdgcn_mfma_f32_16x16x32_bf16(bfr[n], wfr[m], acc[m][n], 0,0,0);
    }
#pragma unroll
    for (int m = 0; m < 4; ++m) {
      int c = wc + m*16 + l15;
      float bc = bm[c];
#pragma unroll
      for (int n = 0; n < 4; ++n) {
        int rl = i0 + wr + n*16 + g*4;
        bf16x4 o;
#pragma unroll
        for (int j = 0; j < 4; ++j) o[j] = (bf16)fmaxf(acc[m][n][j] + bc, 0.f);
        *(bf16x4*)(msgTout + ((size_t)(b*128 + c))*512 + rl) = o;
      }
    }
  }
}

// -------------------------------------------------- fused pool + readout
__global__ __launch_bounds__(256) void pool_readout(
    const bf16* __restrict__ h, const float* __restrict__ mask,
    const float* __restrict__ W1, const float* __restrict__ b1,
    const float* __restrict__ W2, const float* __restrict__ b2,
    float* __restrict__ out) {
  __shared__ float part[3][128];
  __shared__ float pl[128];
  __shared__ float hid[128];
  int b = blockIdx.x, t = threadIdx.x, g = t >> 6, cp = (t & 63)*2;
  float a0 = 0.f, a1 = 0.f;
  for (int n = g*128; n < g*128+128; ++n) {
    float mv = mask[(size_t)b*Nn + n];
    bf16x2 v = *(const bf16x2*)(h + ((size_t)b*Nn + n)*128 + cp);
    a0 = fmaf((float)v[0], mv, a0);
    a1 = fmaf((float)v[1], mv, a1);
  }
  if (g > 0) { part[g-1][cp] = a0; part[g-1][cp+1] = a1; }
  __syncthreads();
  if (g == 0) {
    pl[cp]   = a0 + part[0][cp]   + part[1][cp]   + part[2][cp];
    pl[cp+1] = a1 + part[0][cp+1] + part[1][cp+1] + part[2][cp+1];
  }
  __syncthreads();
  if (t < 128) {
    float a = b1[t];
#pragma unroll 4
    for (int j = 0; j < 128; ++j) a = fmaf(pl[j], W1[j*128 + t], a);
    hid[t] = fmaxf(a, 0.f);
  }
  __syncthreads();
  if (t < 128) {
    float a = b2[t];
#pragma unroll 4
    for (int j = 0; j < 128; ++j) a = fmaf(hid[j], W2[j*128 + t], a);
    out[(size_t)b*128 + t] = a;
  }
}

// -------------------------------------------------- launch
extern "C" void kernel_launch(void* const* d_in, const int* in_sizes, int n_in,
                              void* d_out, int out_size, void* d_ws, size_t ws_size,
                              hipStream_t stream) {
  const float* jets = (const float*)d_in[0];
  const float* mask = (const float*)d_in[1];
  const float* eW0  = (const float*)d_in[2];
  const float* eb0  = (const float*)d_in[3];
  const float* eW1  = (const float*)d_in[4];
  const float* eb1  = (const float*)d_in[5];
  const float* Wm   = (const float*)d_in[6];
  const float* bm   = (const float*)d_in[7];
  const float* Wu   = (const float*)d_in[8];
  const float* bu   = (const float*)d_in[9];
  const float* rW1  = (const float*)d_in[10];
  const float* rb1  = (const float*)d_in[11];
  const float* rW2  = (const float*)d_in[12];
  const float* rb2  = (const float*)d_in[13];
  float* out = (float*)d_out;

  bf16* h     = (bf16*)d_ws;                    // ROWS*128
  bf16* msgTA = h     + (size_t)ROWS*128;       // ROWS*128 (layout [b][c][n])
  bf16* msgTB = msgTA + (size_t)ROWS*128;       // ROWS*128 (ping-pong)
  bf16* WTe   = msgTB + (size_t)ROWS*128;       // 128*128
  bf16* WTm   = WTe   + 128*128;                // 3*128*128
  bf16* WTu   = WTm   + 3*128*128;              // 3*256*128
  float* rsum = (float*)(WTu + 3*256*128);      // ROWS (1/l_i)

  prep_all<<<640, 256, 0, stream>>>(eW1, Wm, Wu, WTe, WTm, WTu);
  embed_msg0<<<ROWS/128, 256, 0, stream>>>(jets, eW0, eb0, WTe, eb1,
                                           WTm, bm, h, msgTA);
  // iter 0 (computes 1/l_i on the fly): msgTA -> msgTB
  iter_fused<true,true><<<Bb*4, 256, 0, stream>>>(
      jets, mask, rsum, msgTA, h,
      WTu, bu, WTm + (size_t)1*128*128, bm + 1*128, msgTB);
  // iter 1: msgTB -> msgTA
  iter_fused<false,true><<<Bb*4, 256, 0, stream>>>(
      jets, mask, rsum, msgTB, h,
      WTu + (size_t)1*256*128, bu + 1*128,
      WTm + (size_t)2*128*128, bm + 2*128, msgTA);
  // iter 2 (no next msg): reads msgTA
  iter_fused<false,false><<<Bb*4, 256, 0, stream>>>(
      jets, mask, rsum, msgTA, h,
      WTu + (size_t)2*256*128, bu + 2*128, nullptr, nullptr, nullptr);

  pool_readout<<<Bb, 256, 0, stream>>>(h, mask, rW1, rb1, rW2, rb2, out);
}